// Round 3
// baseline (430.975 us; speedup 1.0000x reference)
//
#include <hip/hip_runtime.h>
#include <hip/hip_bf16.h>

// B=8, T=2048, D=1024, E=1024
//   k0 : WT = bf16(W^T)                 -> d_out[32MiB..34MiB] (dead before k4)
//   k00: xbf = bf16(x) [B][T][D]        -> d_ws[0:32MiB]   (dead before k2 writes S)
//        xT  = bf16(x^T) [B][D][T]      -> d_ws[64MiB..96MiB] (only if ws >= 96MiB)
//   k1 : y = bf16(xbf@WT^T + b)         -> d_out[0:32MiB]  (deep-pipe MFMA, BK=64)
//   k2 : S[b,t,s] = bf16(y_t.y_s/32)    -> d_ws, lower-triangle tiles (deep-pipe)
//   k2b: col stats m_s, r_s=1/z_s       -> stashed in S's dead zone
//   k3 : P = exp(S-m_s)*r_s in place    (causal-restricted)
//   k4 : out = P @ x  fp32  — fast path: deep-pipe from P and xT;
//        fallback: round-4 scalar-gather version.
//
// Round-3 change (T3+T4 counted-vmcnt deep pipeline, m218 pattern):
//   3 LDS buffer slots, depth-2 prefetch. Per K-step:
//     { issue stage(t+2) -> slot (t+2)%3 ; MFMA on slot t%3 ;
//       s_waitcnt vmcnt(4)  (awaits stage(t+1) ONLY - one tile stays in flight);
//       raw s_barrier }.
//   Hazards: WAR on slot (t+2)%3 == (t-1)%3 closed by barrier at end of t-1
//   (ds_reads complete before their consuming MFMAs, hence before the wave's
//   barrier). RAW on slot (t+1)%3 closed because every wave waits vmcnt(4) on
//   its OWN 4 loads of stage(t+1) before the barrier. Tail: vmcnt(0).
//   96KiB LDS -> 1 block/CU (8 waves) == measured resident occupancy before.
//   s_setprio(1) wraps the MFMA cluster (T5; schedule now has role-split).
//
// MFMA 16x16x32 bf16 frag layouts (HW-verified):
//   A: lane holds A[m=lane&15][k=q*8+j]; B: B[k=q*8+j][n=lane&15]
//   C/D: lane,reg r -> D[row=q*4+r][col=lane&15]
// Swizzled LDS tile (128 rows x 64 shorts, no pad): 16B chunk slot c of row r
// holds logical chunk c ^ (r&7) (pre-swizzled global source, linear LDS dest).

#define B_ 8
#define T_ 2048
#define D_ 1024
#define E_ 1024
#define PIT 56

typedef unsigned short u16;
typedef __attribute__((ext_vector_type(8))) short short8;
typedef __attribute__((ext_vector_type(4))) float floatx4;

__device__ __forceinline__ float b2f(u16 u) {
    unsigned v = ((unsigned)u) << 16;
    float f; __builtin_memcpy(&f, &v, 4); return f;
}
__device__ __forceinline__ u16 f2b(float f) {
    unsigned v; __builtin_memcpy(&v, &f, 4);
    v = (v + 0x7FFFu + ((v >> 16) & 1u)) >> 16;   // RNE
    return (u16)v;
}
__device__ __forceinline__ unsigned pkbf(float a, float b) {
    __hip_bfloat162 h = __float22bfloat162_rn(make_float2(a, b));
    unsigned u; __builtin_memcpy(&u, &h, 4); return u;
}

// async 16B global -> LDS (lds dest = wave-uniform base + lane*16)
__device__ __forceinline__ void gl2lds16(const u16* gp, u16* lp) {
    __builtin_amdgcn_global_load_lds(
        (const __attribute__((address_space(1))) void*)(gp),
        (__attribute__((address_space(3))) void*)(lp), 16, 0, 0);
}

// 8-wave (512-thread) stage of a 128-row x 64-short bf16 tile into swizzled LDS.
// 2 gl2lds per thread (vmcnt +2 per call; one A+B stage pair = 4/thread).
__device__ __forceinline__ void stage8(const u16* src, size_t srow, int kc,
                                       u16* lds, int wid, int lane)
{
    const int rl = lane >> 3, c = lane & 7;
    const int g = ((c ^ rl) << 3);
#pragma unroll
    for (int cc = 0; cc < 2; cc++) {
        const int r = cc * 64 + wid * 8;
        gl2lds16(src + (size_t)(r + rl) * srow + kc + g, &lds[r * 64]);
    }
}

// one BK=64 MFMA step on a staged slot pair (16 mfma, setprio-wrapped)
__device__ __forceinline__ void gemm_step(const u16* As_, const u16* Bs_,
                                          int wr, int wc, int l15, int q, int sw,
                                          floatx4 (&acc)[2][4])
{
    __builtin_amdgcn_s_setprio(1);
#pragma unroll
    for (int h = 0; h < 2; h++) {
        short8 a[2], b2[4];
#pragma unroll
        for (int i = 0; i < 2; i++)
            a[i] = *(const short8*)&As_[(wr + i * 16 + l15) * 64 + (((h * 4 + q) ^ sw) << 3)];
#pragma unroll
        for (int j = 0; j < 4; j++)
            b2[j] = *(const short8*)&Bs_[(wc + j * 16 + l15) * 64 + (((h * 4 + q) ^ sw) << 3)];
#pragma unroll
        for (int i = 0; i < 2; i++)
#pragma unroll
            for (int j = 0; j < 4; j++)
                acc[i][j] = __builtin_amdgcn_mfma_f32_16x16x32_bf16(a[i], b2[j], acc[i][j], 0, 0, 0);
    }
    __builtin_amdgcn_s_setprio(0);
}

// m/r stash inside S's strictly-upper dead zone (batch 0, rows 0..63, cols 1024+).
__device__ __forceinline__ float* mr_ptr(u16* S, int which, int b, int s) {
    const int row = which * 32 + b * 4 + (s >> 9);
    return (float*)(S + (size_t)row * T_ + 1024 + (s & 511) * 2);
}

// ---------------- K0: WT[n][k] = bf16(W[k][n]) ----------------
__global__ __launch_bounds__(256) void k0_wt(const float* __restrict__ W,
                                             u16* __restrict__ WT)
{
    __shared__ float Ws[64 * 68];
    const int tid = threadIdx.x;
    const int k0 = blockIdx.x * 64, n0 = blockIdx.y * 64;
#pragma unroll
    for (int u = 0; u < 4; u++) {
        const int c = tid + 256 * u;
        const int row = c >> 4, c4 = c & 15;
        float4 v = *(const float4*)(W + (size_t)(k0 + row) * E_ + n0 + c4 * 4);
        *(float4*)&Ws[row * 68 + c4 * 4] = v;
    }
    __syncthreads();
#pragma unroll
    for (int u = 0; u < 2; u++) {
        const int c = tid + 256 * u;
        const int n = c >> 3, kc = c & 7;
        unsigned pk[4];
#pragma unroll
        for (int j = 0; j < 4; j++)
            pk[j] = pkbf(Ws[(kc * 8 + 2 * j) * 68 + n], Ws[(kc * 8 + 2 * j + 1) * 68 + n]);
        *(uint4*)(WT + (size_t)(n0 + n) * D_ + k0 + kc * 8) = make_uint4(pk[0], pk[1], pk[2], pk[3]);
    }
}

// ---------------- K00: xbf = bf16(x); optionally xT[b][d][t] = bf16(x[b][t][d]) ----------------
__global__ __launch_bounds__(256) void k00_xt(const float* __restrict__ x,
                                              u16* __restrict__ XT,
                                              u16* __restrict__ xbf,
                                              int do_xt)
{
    __shared__ float Xs[64 * 68];
    const int tid = threadIdx.x;
    const int s0 = blockIdx.x * 64, d0 = blockIdx.y * 64, b = blockIdx.z;
    const float* xb = x + (size_t)b * T_ * D_;
#pragma unroll
    for (int u = 0; u < 4; u++) {
        const int c = tid + 256 * u;
        const int row = c >> 4, c4 = c & 15;
        float4 v = *(const float4*)(xb + (size_t)(s0 + row) * D_ + d0 + c4 * 4);
        *(float4*)&Xs[row * 68 + c4 * 4] = v;
    }
    __syncthreads();
    // row-major bf16 copy (always)
#pragma unroll
    for (int u = 0; u < 2; u++) {
        const int c = tid + 256 * u;
        const int row = c >> 3, off = c & 7;
        unsigned pk[4];
#pragma unroll
        for (int j = 0; j < 4; j++)
            pk[j] = pkbf(Xs[row * 68 + off * 8 + 2 * j], Xs[row * 68 + off * 8 + 2 * j + 1]);
        *(uint4*)(xbf + ((size_t)(b * T_ + s0 + row)) * D_ + d0 + off * 8) =
            make_uint4(pk[0], pk[1], pk[2], pk[3]);
    }
    if (!do_xt) return;
    // transposed bf16 copy (fast path only)
#pragma unroll
    for (int u = 0; u < 2; u++) {
        const int c = tid + 256 * u;
        const int d = c >> 3, sc = c & 7;
        unsigned pk[4];
#pragma unroll
        for (int j = 0; j < 4; j++)
            pk[j] = pkbf(Xs[(sc * 8 + 2 * j) * 68 + d], Xs[(sc * 8 + 2 * j + 1) * 68 + d]);
        *(uint4*)(XT + ((size_t)(b * D_ + d0 + d)) * T_ + s0 + sc * 8) =
            make_uint4(pk[0], pk[1], pk[2], pk[3]);
    }
}

// ---------------- K1: y = bf16(xbf @ WT^T + b), deep-pipe, BK=64 ----------------
__global__ __launch_bounds__(512, 2) void k1_proj(const u16* __restrict__ xbf,
                                                  const u16* __restrict__ WT,
                                                  const float* __restrict__ bias,
                                                  u16* __restrict__ y)
{
    __shared__ u16 As[3][128 * 64];
    __shared__ u16 Bs[3][128 * 64];
    const int tid = threadIdx.x;
    const int lane = tid & 63, wid = tid >> 6;
    const int wr = (wid >> 1) * 32, wc = (wid & 1) * 64;
    const int l15 = lane & 15, q = lane >> 4;
    const int sw = l15 & 7;
    // XCD-chunked swizzle: XCD c owns m-tiles [16c,16c+16) (A panel ~4MB -> L2-hot)
    const int lin = blockIdx.y * 8 + blockIdx.x;      // 1024 blocks, %8==0
    const int v = (lin & 7) * 128 + (lin >> 3);
    const int n0 = (v & 7) * 128, m0 = (v >> 3) * 128;
    const u16* Ab = xbf + (size_t)m0 * D_;
    const u16* Bb = WT + (size_t)n0 * D_;

    floatx4 acc[2][4];
#pragma unroll
    for (int i = 0; i < 2; i++)
#pragma unroll
        for (int j = 0; j < 4; j++) acc[i][j] = (floatx4){0.f, 0.f, 0.f, 0.f};

    stage8(Ab, D_, 0, As[0], wid, lane);
    stage8(Bb, D_, 0, Bs[0], wid, lane);
    stage8(Ab, D_, 64, As[1], wid, lane);
    stage8(Bb, D_, 64, Bs[1], wid, lane);
    asm volatile("s_waitcnt vmcnt(4)" ::: "memory");
    __builtin_amdgcn_s_barrier();
    int cs = 0, ss = 2;
    for (int t = 0; t < 16; t++) {
        if (t + 2 < 16) {
            stage8(Ab, D_, (t + 2) * 64, As[ss], wid, lane);
            stage8(Bb, D_, (t + 2) * 64, Bs[ss], wid, lane);
        }
        gemm_step(As[cs], Bs[cs], wr, wc, l15, q, sw, acc);
        if (t < 15) {
            if (t + 2 < 16) asm volatile("s_waitcnt vmcnt(4)" ::: "memory");
            else            asm volatile("s_waitcnt vmcnt(0)" ::: "memory");
            __builtin_amdgcn_s_barrier();
        }
        cs = cs == 2 ? 0 : cs + 1;
        ss = ss == 2 ? 0 : ss + 1;
    }
    float bv[4];
#pragma unroll
    for (int j = 0; j < 4; j++) bv[j] = bias[n0 + wc + j * 16 + l15];
#pragma unroll
    for (int i = 0; i < 2; i++)
#pragma unroll
        for (int j = 0; j < 4; j++)
#pragma unroll
            for (int r = 0; r < 4; r++) {
                const int gm = m0 + wr + i * 16 + q * 4 + r;
                const int gn = n0 + wc + j * 16 + l15;
                y[(size_t)gm * E_ + gn] = f2b(acc[i][j][r] + bv[j]);
            }
}

// ---------------- K2: S tiles, deep-pipe, BK=64 ----------------
__global__ __launch_bounds__(512, 2) void k2_score(const u16* __restrict__ y,
                                                   u16* __restrict__ S)
{
    __shared__ u16 As[3][128 * 64];
    __shared__ u16 Bs[3][128 * 64];
    const int tid = threadIdx.x;
    const int lane = tid & 63, wid = tid >> 6;
    const int wr = (wid >> 1) * 32, wc = (wid & 1) * 64;
    const int l15 = lane & 15, q = lane >> 4;
    const int sw = l15 & 7;
    // XCD-chunked swizzle over the 136 triangular tiles (136%8==0)
    int idx = (blockIdx.x & 7) * 17 + (blockIdx.x >> 3);
    int it = 0, base = 0;
    while (base + it + 1 <= idx) { base += it + 1; it++; }
    const int js = idx - base;
    const int t0 = it * 128, s0 = js * 128;
    const int b = blockIdx.y;
    const u16* yb = y + (size_t)b * T_ * E_;
    const u16* Ab = yb + (size_t)t0 * E_;
    const u16* Bb = yb + (size_t)s0 * E_;

    floatx4 acc[2][4];
#pragma unroll
    for (int i = 0; i < 2; i++)
#pragma unroll
        for (int j = 0; j < 4; j++) acc[i][j] = (floatx4){0.f, 0.f, 0.f, 0.f};

    stage8(Ab, E_, 0, As[0], wid, lane);
    stage8(Bb, E_, 0, Bs[0], wid, lane);
    stage8(Ab, E_, 64, As[1], wid, lane);
    stage8(Bb, E_, 64, Bs[1], wid, lane);
    asm volatile("s_waitcnt vmcnt(4)" ::: "memory");
    __builtin_amdgcn_s_barrier();
    int cs = 0, ss = 2;
    for (int t = 0; t < 16; t++) {
        if (t + 2 < 16) {
            stage8(Ab, E_, (t + 2) * 64, As[ss], wid, lane);
            stage8(Bb, E_, (t + 2) * 64, Bs[ss], wid, lane);
        }
        gemm_step(As[cs], Bs[cs], wr, wc, l15, q, sw, acc);
        if (t < 15) {
            if (t + 2 < 16) asm volatile("s_waitcnt vmcnt(4)" ::: "memory");
            else            asm volatile("s_waitcnt vmcnt(0)" ::: "memory");
            __builtin_amdgcn_s_barrier();
        }
        cs = cs == 2 ? 0 : cs + 1;
        ss = ss == 2 ? 0 : ss + 1;
    }
#pragma unroll
    for (int i = 0; i < 2; i++)
#pragma unroll
        for (int j = 0; j < 4; j++)
#pragma unroll
            for (int r = 0; r < 4; r++) {
                const int t = t0 + wr + i * 16 + q * 4 + r;
                const int s = s0 + wc + j * 16 + l15;
                u16 o = (t < s) ? (u16)0xFF7F : f2b(acc[i][j][r] * 0.03125f);
                S[((size_t)(b * T_ + t)) * T_ + s] = o;
            }
}

// ---------------- K2b: per-column (m, 1/z) over t >= s ----------------
__global__ __launch_bounds__(256) void k2b_stats(u16* __restrict__ S)
{
    __shared__ u16 St[64 * 64];
    __shared__ float sm[4][64], sz[4][64];
    const int tid = threadIdx.x;
    const int lane = tid & 63, w = tid >> 6;
    const int b = blockIdx.y;
    const int s0 = blockIdx.x * 64;
    const u16* Sb = S + (size_t)b * T_ * T_;
    float m = -3e38f, z = 0.f;
    for (int t0 = s0; t0 < T_; t0 += 64) {
        __syncthreads();
#pragma unroll
        for (int u = 0; u < 2; u++) {
            const int c = tid * 2 + u;
            const int row = c >> 3, off = c & 7;
            *(uint4*)&St[row * 64 + off * 8] =
                *(const uint4*)(Sb + (size_t)(t0 + row) * T_ + s0 + off * 8);
        }
        __syncthreads();
#pragma unroll
        for (int i = 0; i < 16; i++) {
            const float v = b2f(St[(w * 16 + i) * 64 + lane]);
            if (v > m) { z = z * __expf(m - v) + 1.f; m = v; }
            else z += __expf(v - m);
        }
    }
    sm[w][lane] = m; sz[w][lane] = z;
    __syncthreads();
    if (tid < 64) {
        float mm = sm[0][tid];
#pragma unroll
        for (int rr = 1; rr < 4; rr++) mm = fmaxf(mm, sm[rr][tid]);
        float zz = 0.f;
#pragma unroll
        for (int rr = 0; rr < 4; rr++) zz += sz[rr][tid] * __expf(sm[rr][tid] - mm);
        *mr_ptr(S, 0, b, s0 + tid) = mm;
        *mr_ptr(S, 1, b, s0 + tid) = 1.0f / zz;
    }
}

// ---------------- K3: P = exp(S - m_s) * r_s  (in place, causal-restricted) ----------------
__global__ __launch_bounds__(256) void k3_pnorm(u16* __restrict__ S)
{
    const int row = blockIdx.x;          // b*T + t
    const int b = row >> 11;
    const int t = row & (T_ - 1);
    const int sEnd = ((t >> 7) + 1) << 7;
    const int s0 = threadIdx.x * 8;
    if (s0 >= sEnd) return;
    u16* Sp = S + (size_t)row * T_ + s0;
    const float* mp = mr_ptr(S, 0, b, s0);
    const float* rp = mr_ptr(S, 1, b, s0);
    float mv[8], rv[8];
    *(float4*)&mv[0] = *(const float4*)mp;
    *(float4*)&mv[4] = *((const float4*)mp + 1);
    *(float4*)&rv[0] = *(const float4*)rp;
    *(float4*)&rv[4] = *((const float4*)rp + 1);
    ushort4 v0 = *(ushort4*)Sp;
    ushort4 v1 = *(ushort4*)(Sp + 4);
    u16 vv[8] = { v0.x, v0.y, v0.z, v0.w, v1.x, v1.y, v1.z, v1.w };
    u16 ov[8];
#pragma unroll
    for (int i = 0; i < 8; i++) {
        const int s = s0 + i;
        float p = 0.f;
        if (s <= t) p = __expf(b2f(vv[i]) - mv[i]) * rv[i];
        ov[i] = f2b(p);
    }
    *(ushort4*)Sp       = make_ushort4(ov[0], ov[1], ov[2], ov[3]);
    *(ushort4*)(Sp + 4) = make_ushort4(ov[4], ov[5], ov[6], ov[7]);
}

// ---------------- K4 fast: out = P @ xT^T, deep-pipe, BK=64 ----------------
__global__ __launch_bounds__(512, 2) void k4_fast(const u16* __restrict__ P,
                                                  const u16* __restrict__ XT,
                                                  float* __restrict__ out)
{
    __shared__ u16 As[3][128 * 64];
    __shared__ u16 Bs[3][128 * 64];
    const int tid = threadIdx.x;
    const int lane = tid & 63, wid = tid >> 6;
    const int wr = (wid >> 1) * 32, wc = (wid & 1) * 64;
    const int l15 = lane & 15, q = lane >> 4;
    const int sw = l15 & 7;
    const int it = (T_ / 128 - 1) - blockIdx.y;   // heavy tiles first
    const int t0 = it * 128;
    const int d0 = blockIdx.x * 128;
    const int b = blockIdx.z;
    const u16* Pb = P + (size_t)b * T_ * T_ + (size_t)t0 * T_;
    const u16* Xb = XT + (size_t)(b * D_ + d0) * T_;

    floatx4 acc[2][4];
#pragma unroll
    for (int i = 0; i < 2; i++)
#pragma unroll
        for (int j = 0; j < 4; j++) acc[i][j] = (floatx4){0.f, 0.f, 0.f, 0.f};

    const int nt = (it + 1) * 2;      // K-steps of 64 up to t0+128 (>= 2)
    stage8(Pb, T_, 0, As[0], wid, lane);
    stage8(Xb, T_, 0, Bs[0], wid, lane);
    stage8(Pb, T_, 64, As[1], wid, lane);
    stage8(Xb, T_, 64, Bs[1], wid, lane);
    asm volatile("s_waitcnt vmcnt(4)" ::: "memory");
    __builtin_amdgcn_s_barrier();
    int cs = 0, ss = 2;
    for (int t = 0; t < nt; t++) {
        if (t + 2 < nt) {
            stage8(Pb, T_, (t + 2) * 64, As[ss], wid, lane);
            stage8(Xb, T_, (t + 2) * 64, Bs[ss], wid, lane);
        }
        gemm_step(As[cs], Bs[cs], wr, wc, l15, q, sw, acc);
        if (t < nt - 1) {
            if (t + 2 < nt) asm volatile("s_waitcnt vmcnt(4)" ::: "memory");
            else            asm volatile("s_waitcnt vmcnt(0)" ::: "memory");
            __builtin_amdgcn_s_barrier();
        }
        cs = cs == 2 ? 0 : cs + 1;
        ss = ss == 2 ? 0 : ss + 1;
    }
#pragma unroll
    for (int i = 0; i < 2; i++)
#pragma unroll
        for (int j = 0; j < 4; j++)
#pragma unroll
            for (int r = 0; r < 4; r++) {
                const int gt = t0 + wr + i * 16 + q * 4 + r;
                const int gd = d0 + wc + j * 16 + l15;
                out[(size_t)(b * T_ + gt) * D_ + gd] = acc[i][j][r];
            }
}

// ---------------- K4 fallback (round-4): scalar-gather B-stage ----------------
__global__ __launch_bounds__(256) void k4_fb(const u16* __restrict__ P,
                                             const float* __restrict__ x,
                                             float* __restrict__ out)
{
    __shared__ u16 As[128 * PIT];
    __shared__ u16 Bs[128 * PIT];
    const int tid = threadIdx.x;
    const int lane = tid & 63, wid = tid >> 6;
    const int wr = (wid >> 1) * 64, wc = (wid & 1) * 64;
    const int l15 = lane & 15, q = lane >> 4;
    const int it = (T_ / 128 - 1) - blockIdx.y;
    const int t0 = it * 128;
    const int d0 = blockIdx.x * 128;
    const int b = blockIdx.z;
    const u16* Pb = P + (size_t)b * T_ * T_;
    const float* xb = x + (size_t)b * T_ * D_;
    const int gn = tid & 127;
    const int kh0 = (tid >> 7) * 2;

    floatx4 acc[4][4];
#pragma unroll
    for (int i = 0; i < 4; i++)
#pragma unroll
        for (int j = 0; j < 4; j++) acc[i][j] = (floatx4){0.f, 0.f, 0.f, 0.f};

    const int kend = t0 + 128;
    for (int k0 = 0; k0 < kend; k0 += 32) {
        __syncthreads();
#pragma unroll
        for (int u = 0; u < 2; u++) {
            const int c = tid * 2 + u;
            const int row = c >> 2, off = c & 3;
            *(uint4*)&As[row * PIT + off * 8] =
                *(const uint4*)(Pb + (size_t)(t0 + row) * T_ + k0 + off * 8);
        }
#pragma unroll
        for (int u = 0; u < 2; u++) {
            const int kh = kh0 + u;
            float f[8];
#pragma unroll
            for (int j = 0; j < 8; j++)
                f[j] = xb[(size_t)(k0 + kh * 8 + j) * D_ + d0 + gn];
            uint4 pk = make_uint4(pkbf(f[0], f[1]), pkbf(f[2], f[3]),
                                  pkbf(f[4], f[5]), pkbf(f[6], f[7]));
            *(uint4*)&Bs[gn * PIT + kh * 8] = pk;
        }
        __syncthreads();
        short8 a[4], b2[4];
#pragma unroll
        for (int i = 0; i < 4; i++) a[i] = *(const short8*)&As[(wr + i * 16 + l15) * PIT + q * 8];
#pragma unroll
        for (int j = 0; j < 4; j++) b2[j] = *(const short8*)&Bs[(wc + j * 16 + l15) * PIT + q * 8];
#pragma unroll
        for (int i = 0; i < 4; i++)
#pragma unroll
            for (int j = 0; j < 4; j++)
                acc[i][j] = __builtin_amdgcn_mfma_f32_16x16x32_bf16(a[i], b2[j], acc[i][j], 0, 0, 0);
    }
#pragma unroll
    for (int i = 0; i < 4; i++)
#pragma unroll
        for (int j = 0; j < 4; j++)
#pragma unroll
            for (int r = 0; r < 4; r++) {
                const int gt = t0 + wr + i * 16 + q * 4 + r;
                const int gd = d0 + wc + j * 16 + l15;
                out[(size_t)(b * T_ + gt) * D_ + gd] = acc[i][j][r];
            }
}

extern "C" void kernel_launch(void* const* d_in, const int* in_sizes, int n_in,
                              void* d_out, int out_size, void* d_ws, size_t ws_size,
                              hipStream_t stream)
{
    const float* x    = (const float*)d_in[0];
    const float* W    = (const float*)d_in[1];
    const float* bias = (const float*)d_in[2];
    float* outf = (float*)d_out;
    u16*   y    = (u16*)d_out;                  // bf16, first 32 MiB of d_out
    u16*   WT   = y + ((size_t)1 << 24);        // 32MiB..34MiB of d_out (dead before k4)
    u16*   S    = (u16*)d_ws;                   // 64 MiB (m/r stashed in dead zone)
    u16*   xbf  = S;                            // bf16 x, ws[0:32MiB] (dead before k2)
    u16*   XT   = S + ((size_t)1 << 25);        // ws+64MiB..+96MiB (fast path only)
    const bool fast = ws_size >= ((size_t)96 << 20);

    dim3 g0(D_ / 64, E_ / 64);            // (16,16)
    k0_wt<<<g0, 256, 0, stream>>>(W, WT);

    dim3 g00(T_ / 64, D_ / 64, B_);       // (32,16,8)
    k00_xt<<<g00, 256, 0, stream>>>(x, XT, xbf, fast ? 1 : 0);

    dim3 g1(E_ / 128, (B_ * T_) / 128);   // (8, 128)
    k1_proj<<<g1, 512, 0, stream>>>(xbf, WT, bias, y);

    dim3 g2(136, B_);
    k2_score<<<g2, 512, 0, stream>>>(y, S);

    dim3 g2b(T_ / 64, B_);                // (32, 8)
    k2b_stats<<<g2b, 256, 0, stream>>>(S);

    dim3 g3(B_ * T_);
    k3_pnorm<<<g3, 256, 0, stream>>>(S);

    dim3 g4(D_ / 128, T_ / 128, B_);      // (8, 16, 8)
    if (fast) k4_fast<<<g4, 512, 0, stream>>>(S, XT, outf);
    else      k4_fb  <<<g4, 256, 0, stream>>>(S, x, outf);
}

// Round 4
// 379.524 us; speedup vs baseline: 1.1356x; 1.1356x over previous
//
#include <hip/hip_runtime.h>
#include <hip/hip_bf16.h>

// B=8, T=2048, D=1024, E=1024
//   k0 : WT = bf16(W^T)                 -> d_out[32MiB..34MiB] (dead before k4)
//   k00: xbf = bf16(x) [B][T][D]        -> d_ws[0:32MiB]   (dead before k2 writes S)
//        xT  = bf16(x^T) [B][D][T]      -> d_ws[64MiB..96MiB] (only if ws >= 96MiB)
//   k1 : y = bf16(xbf@WT^T + b)         -> d_out[0:32MiB]  (2-phase dbuf MFMA, BK=64)
//   k2 : S[b,t,s] = bf16(y_t.y_s/32)    -> d_ws, lower-triangle tiles (2-phase dbuf)
//   k2b: col stats m_s, r_s=1/z_s       -> stashed in S's dead zone
//   k4 : out = softmax-normalize(S) @ x fp32 — fast path fuses the k3 P-pass:
//        A-stage = reg-load S, exp(S-m_s)*r_s in VALU (late, after MFMAs),
//        swizzled ds_write (T14 issue-early/write-late). B = xT via gl2lds.
//   k3+k4_fb: fallback path (ws < 96MiB) unchanged.
//
// Round-4: REVERT round-3 deep-pipe (96KiB LDS dropped 2nd resident block:
//   occ 26->15.6%, MfmaUtil 20->14%, k4 68->100us). 2-phase + 2 blocks/CU is
//   the measured optimum for this structure. New change: k3 fused into k4.
//
// MFMA 16x16x32 bf16 frag layouts (HW-verified):
//   A: lane holds A[m=lane&15][k=q*8+j]; B: B[k=q*8+j][n=lane&15]
//   C/D: lane,reg r -> D[row=q*4+r][col=lane&15]
// Swizzled LDS tile (128 rows x 64 shorts, no pad): 16B chunk slot c of row r
// holds logical chunk c ^ (r&7) (pre-swizzled global source, linear LDS dest;
// reg-staged A writes the same layout via ds_write_b128).

#define B_ 8
#define T_ 2048
#define D_ 1024
#define E_ 1024
#define PIT 56

typedef unsigned short u16;
typedef __attribute__((ext_vector_type(8))) short short8;
typedef __attribute__((ext_vector_type(4))) float floatx4;

__device__ __forceinline__ float b2f(u16 u) {
    unsigned v = ((unsigned)u) << 16;
    float f; __builtin_memcpy(&f, &v, 4); return f;
}
__device__ __forceinline__ u16 f2b(float f) {
    unsigned v; __builtin_memcpy(&v, &f, 4);
    v = (v + 0x7FFFu + ((v >> 16) & 1u)) >> 16;   // RNE
    return (u16)v;
}
__device__ __forceinline__ unsigned pkbf(float a, float b) {
    __hip_bfloat162 h = __float22bfloat162_rn(make_float2(a, b));
    unsigned u; __builtin_memcpy(&u, &h, 4); return u;
}

// async 16B global -> LDS (lds dest = wave-uniform base + lane*16)
__device__ __forceinline__ void gl2lds16(const u16* gp, u16* lp) {
    __builtin_amdgcn_global_load_lds(
        (const __attribute__((address_space(1))) void*)(gp),
        (__attribute__((address_space(3))) void*)(lp), 16, 0, 0);
}

// 8-wave (512-thread) stage of a 128-row x 64-short bf16 tile into swizzled LDS.
__device__ __forceinline__ void stage8(const u16* src, size_t srow, int kc,
                                       u16* lds, int wid, int lane)
{
    const int rl = lane >> 3, c = lane & 7;
    const int g = ((c ^ rl) << 3);
#pragma unroll
    for (int cc = 0; cc < 2; cc++) {
        const int r = cc * 64 + wid * 8;
        gl2lds16(src + (size_t)(r + rl) * srow + kc + g, &lds[r * 64]);
    }
}

// one BK=64 MFMA step on a staged slot pair (16 mfma)
__device__ __forceinline__ void gemm_step(const u16* As_, const u16* Bs_,
                                          int wr, int wc, int l15, int q, int sw,
                                          floatx4 (&acc)[2][4])
{
#pragma unroll
    for (int h = 0; h < 2; h++) {
        short8 a[2], b2[4];
#pragma unroll
        for (int i = 0; i < 2; i++)
            a[i] = *(const short8*)&As_[(wr + i * 16 + l15) * 64 + (((h * 4 + q) ^ sw) << 3)];
#pragma unroll
        for (int j = 0; j < 4; j++)
            b2[j] = *(const short8*)&Bs_[(wc + j * 16 + l15) * 64 + (((h * 4 + q) ^ sw) << 3)];
#pragma unroll
        for (int i = 0; i < 2; i++)
#pragma unroll
            for (int j = 0; j < 4; j++)
                acc[i][j] = __builtin_amdgcn_mfma_f32_16x16x32_bf16(a[i], b2[j], acc[i][j], 0, 0, 0);
    }
}

// m/r stash inside S's strictly-upper dead zone (batch 0, rows 0..63, cols 1024+).
__device__ __forceinline__ float* mr_ptr(u16* S, int which, int b, int s) {
    const int row = which * 32 + b * 4 + (s >> 9);
    return (float*)(S + (size_t)row * T_ + 1024 + (s & 511) * 2);
}
__device__ __forceinline__ const float* mr_cptr(const u16* S, int which, int b, int s) {
    const int row = which * 32 + b * 4 + (s >> 9);
    return (const float*)(S + (size_t)row * T_ + 1024 + (s & 511) * 2);
}

// ---- fused-P helpers (k4 fast path) ----
// issue: per-thread 2x16B raw-S loads (pre-swizzled source chunks)
__device__ __forceinline__ void aload(const u16* Pb, int kc, int wid, int lane,
                                      uint4 (&av)[2])
{
    const int rl = lane >> 3, c = lane & 7;
    const int g = ((c ^ rl) << 3);
#pragma unroll
    for (int cc = 0; cc < 2; cc++) {
        const int r = cc * 64 + wid * 8;
        av[cc] = *(const uint4*)(Pb + (size_t)(r + rl) * T_ + kc + g);
    }
}
// per-column m/r for this thread's 8 s-values (same for both row-chunks)
__device__ __forceinline__ void mrload(const u16* S, int b, int kc, int lane,
                                       float (&mv)[8], float (&rv)[8])
{
    const int rl = lane >> 3, c = lane & 7;
    const int g = ((c ^ rl) << 3);
    const float* mp = mr_cptr(S, 0, b, kc + g);
    const float* rp = mr_cptr(S, 1, b, kc + g);
    *(float4*)&mv[0] = *(const float4*)mp;
    *(float4*)&mv[4] = *((const float4*)mp + 1);
    *(float4*)&rv[0] = *(const float4*)rp;
    *(float4*)&rv[4] = *((const float4*)rp + 1);
}
// late: P = exp(S-m)*r (masked entries are -3.4e38 -> exp -> 0), pack, ds_write
__device__ __forceinline__ void awrite(u16* lds, int wid, int lane,
                                       const uint4 (&av)[2],
                                       const float (&mv)[8], const float (&rv)[8])
{
    const int rl = lane >> 3, c = lane & 7;
#pragma unroll
    for (int cc = 0; cc < 2; cc++) {
        const int r = cc * 64 + wid * 8;
        const u16* vv = (const u16*)&av[cc];
        unsigned pk[4];
#pragma unroll
        for (int j = 0; j < 4; j++) {
            const float p0 = __expf(b2f(vv[2 * j])     - mv[2 * j])     * rv[2 * j];
            const float p1 = __expf(b2f(vv[2 * j + 1]) - mv[2 * j + 1]) * rv[2 * j + 1];
            pk[j] = pkbf(p0, p1);
        }
        *(uint4*)&lds[(size_t)(r + rl) * 64 + c * 8] = make_uint4(pk[0], pk[1], pk[2], pk[3]);
    }
}

// ---------------- K0: WT[n][k] = bf16(W[k][n]) ----------------
__global__ __launch_bounds__(256) void k0_wt(const float* __restrict__ W,
                                             u16* __restrict__ WT)
{
    __shared__ float Ws[64 * 68];
    const int tid = threadIdx.x;
    const int k0 = blockIdx.x * 64, n0 = blockIdx.y * 64;
#pragma unroll
    for (int u = 0; u < 4; u++) {
        const int c = tid + 256 * u;
        const int row = c >> 4, c4 = c & 15;
        float4 v = *(const float4*)(W + (size_t)(k0 + row) * E_ + n0 + c4 * 4);
        *(float4*)&Ws[row * 68 + c4 * 4] = v;
    }
    __syncthreads();
#pragma unroll
    for (int u = 0; u < 2; u++) {
        const int c = tid + 256 * u;
        const int n = c >> 3, kc = c & 7;
        unsigned pk[4];
#pragma unroll
        for (int j = 0; j < 4; j++)
            pk[j] = pkbf(Ws[(kc * 8 + 2 * j) * 68 + n], Ws[(kc * 8 + 2 * j + 1) * 68 + n]);
        *(uint4*)(WT + (size_t)(n0 + n) * D_ + k0 + kc * 8) = make_uint4(pk[0], pk[1], pk[2], pk[3]);
    }
}

// ---------------- K00: xbf = bf16(x); optionally xT[b][d][t] = bf16(x[b][t][d]) ----------------
__global__ __launch_bounds__(256) void k00_xt(const float* __restrict__ x,
                                              u16* __restrict__ XT,
                                              u16* __restrict__ xbf,
                                              int do_xt)
{
    __shared__ float Xs[64 * 68];
    const int tid = threadIdx.x;
    const int s0 = blockIdx.x * 64, d0 = blockIdx.y * 64, b = blockIdx.z;
    const float* xb = x + (size_t)b * T_ * D_;
#pragma unroll
    for (int u = 0; u < 4; u++) {
        const int c = tid + 256 * u;
        const int row = c >> 4, c4 = c & 15;
        float4 v = *(const float4*)(xb + (size_t)(s0 + row) * D_ + d0 + c4 * 4);
        *(float4*)&Xs[row * 68 + c4 * 4] = v;
    }
    __syncthreads();
    // row-major bf16 copy (always)
#pragma unroll
    for (int u = 0; u < 2; u++) {
        const int c = tid + 256 * u;
        const int row = c >> 3, off = c & 7;
        unsigned pk[4];
#pragma unroll
        for (int j = 0; j < 4; j++)
            pk[j] = pkbf(Xs[row * 68 + off * 8 + 2 * j], Xs[row * 68 + off * 8 + 2 * j + 1]);
        *(uint4*)(xbf + ((size_t)(b * T_ + s0 + row)) * D_ + d0 + off * 8) =
            make_uint4(pk[0], pk[1], pk[2], pk[3]);
    }
    if (!do_xt) return;
    // transposed bf16 copy (fast path only)
#pragma unroll
    for (int u = 0; u < 2; u++) {
        const int c = tid + 256 * u;
        const int d = c >> 3, sc = c & 7;
        unsigned pk[4];
#pragma unroll
        for (int j = 0; j < 4; j++)
            pk[j] = pkbf(Xs[(sc * 8 + 2 * j) * 68 + d], Xs[(sc * 8 + 2 * j + 1) * 68 + d]);
        *(uint4*)(XT + ((size_t)(b * D_ + d0 + d)) * T_ + s0 + sc * 8) =
            make_uint4(pk[0], pk[1], pk[2], pk[3]);
    }
}

// ---------------- K1: y = bf16(xbf @ WT^T + b), 2-phase dbuf, BK=64 ----------------
__global__ __launch_bounds__(512, 4) void k1_proj(const u16* __restrict__ xbf,
                                                  const u16* __restrict__ WT,
                                                  const float* __restrict__ bias,
                                                  u16* __restrict__ y)
{
    __shared__ u16 As[2][128 * 64];
    __shared__ u16 Bs[2][128 * 64];
    const int tid = threadIdx.x;
    const int lane = tid & 63, wid = tid >> 6;
    const int wr = (wid >> 1) * 32, wc = (wid & 1) * 64;
    const int l15 = lane & 15, q = lane >> 4;
    const int sw = l15 & 7;
    // XCD-chunked swizzle: XCD c owns m-tiles [16c,16c+16) (A panel ~4MB -> L2-hot)
    const int lin = blockIdx.y * 8 + blockIdx.x;      // 1024 blocks, %8==0
    const int v = (lin & 7) * 128 + (lin >> 3);
    const int n0 = (v & 7) * 128, m0 = (v >> 3) * 128;
    const u16* Ab = xbf + (size_t)m0 * D_;
    const u16* Bb = WT + (size_t)n0 * D_;

    floatx4 acc[2][4];
#pragma unroll
    for (int i = 0; i < 2; i++)
#pragma unroll
        for (int j = 0; j < 4; j++) acc[i][j] = (floatx4){0.f, 0.f, 0.f, 0.f};

    stage8(Ab, D_, 0, As[0], wid, lane);
    stage8(Bb, D_, 0, Bs[0], wid, lane);
    __syncthreads();
    int cur = 0;
    for (int t = 0; t < 16; t++) {
        if (t + 1 < 16) {
            stage8(Ab, D_, (t + 1) * 64, As[cur ^ 1], wid, lane);
            stage8(Bb, D_, (t + 1) * 64, Bs[cur ^ 1], wid, lane);
        }
        gemm_step(As[cur], Bs[cur], wr, wc, l15, q, sw, acc);
        __syncthreads();
        cur ^= 1;
    }
    float bv[4];
#pragma unroll
    for (int j = 0; j < 4; j++) bv[j] = bias[n0 + wc + j * 16 + l15];
#pragma unroll
    for (int i = 0; i < 2; i++)
#pragma unroll
        for (int j = 0; j < 4; j++)
#pragma unroll
            for (int r = 0; r < 4; r++) {
                const int gm = m0 + wr + i * 16 + q * 4 + r;
                const int gn = n0 + wc + j * 16 + l15;
                y[(size_t)gm * E_ + gn] = f2b(acc[i][j][r] + bv[j]);
            }
}

// ---------------- K2: S tiles, 2-phase dbuf, BK=64 ----------------
__global__ __launch_bounds__(512, 4) void k2_score(const u16* __restrict__ y,
                                                   u16* __restrict__ S)
{
    __shared__ u16 As[2][128 * 64];
    __shared__ u16 Bs[2][128 * 64];
    const int tid = threadIdx.x;
    const int lane = tid & 63, wid = tid >> 6;
    const int wr = (wid >> 1) * 32, wc = (wid & 1) * 64;
    const int l15 = lane & 15, q = lane >> 4;
    const int sw = l15 & 7;
    // XCD-chunked swizzle over the 136 triangular tiles (136%8==0)
    int idx = (blockIdx.x & 7) * 17 + (blockIdx.x >> 3);
    int it = 0, base = 0;
    while (base + it + 1 <= idx) { base += it + 1; it++; }
    const int js = idx - base;
    const int t0 = it * 128, s0 = js * 128;
    const int b = blockIdx.y;
    const u16* yb = y + (size_t)b * T_ * E_;
    const u16* Ab = yb + (size_t)t0 * E_;
    const u16* Bb = yb + (size_t)s0 * E_;

    floatx4 acc[2][4];
#pragma unroll
    for (int i = 0; i < 2; i++)
#pragma unroll
        for (int j = 0; j < 4; j++) acc[i][j] = (floatx4){0.f, 0.f, 0.f, 0.f};

    stage8(Ab, E_, 0, As[0], wid, lane);
    stage8(Bb, E_, 0, Bs[0], wid, lane);
    __syncthreads();
    int cur = 0;
    for (int t = 0; t < 16; t++) {
        if (t + 1 < 16) {
            stage8(Ab, E_, (t + 1) * 64, As[cur ^ 1], wid, lane);
            stage8(Bb, E_, (t + 1) * 64, Bs[cur ^ 1], wid, lane);
        }
        gemm_step(As[cur], Bs[cur], wr, wc, l15, q, sw, acc);
        __syncthreads();
        cur ^= 1;
    }
#pragma unroll
    for (int i = 0; i < 2; i++)
#pragma unroll
        for (int j = 0; j < 4; j++)
#pragma unroll
            for (int r = 0; r < 4; r++) {
                const int t = t0 + wr + i * 16 + q * 4 + r;
                const int s = s0 + wc + j * 16 + l15;
                u16 o = (t < s) ? (u16)0xFF7F : f2b(acc[i][j][r] * 0.03125f);
                S[((size_t)(b * T_ + t)) * T_ + s] = o;
            }
}

// ---------------- K2b: per-column (m, 1/z) over t >= s ----------------
__global__ __launch_bounds__(256) void k2b_stats(u16* __restrict__ S)
{
    __shared__ u16 St[64 * 64];
    __shared__ float sm[4][64], sz[4][64];
    const int tid = threadIdx.x;
    const int lane = tid & 63, w = tid >> 6;
    const int b = blockIdx.y;
    const int s0 = blockIdx.x * 64;
    const u16* Sb = S + (size_t)b * T_ * T_;
    float m = -3e38f, z = 0.f;
    for (int t0 = s0; t0 < T_; t0 += 64) {
        __syncthreads();
#pragma unroll
        for (int u = 0; u < 2; u++) {
            const int c = tid * 2 + u;
            const int row = c >> 3, off = c & 7;
            *(uint4*)&St[row * 64 + off * 8] =
                *(const uint4*)(Sb + (size_t)(t0 + row) * T_ + s0 + off * 8);
        }
        __syncthreads();
#pragma unroll
        for (int i = 0; i < 16; i++) {
            const float v = b2f(St[(w * 16 + i) * 64 + lane]);
            if (v > m) { z = z * __expf(m - v) + 1.f; m = v; }
            else z += __expf(v - m);
        }
    }
    sm[w][lane] = m; sz[w][lane] = z;
    __syncthreads();
    if (tid < 64) {
        float mm = sm[0][tid];
#pragma unroll
        for (int rr = 1; rr < 4; rr++) mm = fmaxf(mm, sm[rr][tid]);
        float zz = 0.f;
#pragma unroll
        for (int rr = 0; rr < 4; rr++) zz += sz[rr][tid] * __expf(sm[rr][tid] - mm);
        *mr_ptr(S, 0, b, s0 + tid) = mm;
        *mr_ptr(S, 1, b, s0 + tid) = 1.0f / zz;
    }
}

// ---------------- K3: P = exp(S - m_s) * r_s  (fallback path only) ----------------
__global__ __launch_bounds__(256) void k3_pnorm(u16* __restrict__ S)
{
    const int row = blockIdx.x;          // b*T + t
    const int b = row >> 11;
    const int t = row & (T_ - 1);
    const int sEnd = ((t >> 7) + 1) << 7;
    const int s0 = threadIdx.x * 8;
    if (s0 >= sEnd) return;
    u16* Sp = S + (size_t)row * T_ + s0;
    const float* mp = mr_ptr(S, 0, b, s0);
    const float* rp = mr_ptr(S, 1, b, s0);
    float mv[8], rv[8];
    *(float4*)&mv[0] = *(const float4*)mp;
    *(float4*)&mv[4] = *((const float4*)mp + 1);
    *(float4*)&rv[0] = *(const float4*)rp;
    *(float4*)&rv[4] = *((const float4*)rp + 1);
    ushort4 v0 = *(ushort4*)Sp;
    ushort4 v1 = *(ushort4*)(Sp + 4);
    u16 vv[8] = { v0.x, v0.y, v0.z, v0.w, v1.x, v1.y, v1.z, v1.w };
    u16 ov[8];
#pragma unroll
    for (int i = 0; i < 8; i++) {
        const int s = s0 + i;
        float p = 0.f;
        if (s <= t) p = __expf(b2f(vv[i]) - mv[i]) * rv[i];
        ov[i] = f2b(p);
    }
    *(ushort4*)Sp       = make_ushort4(ov[0], ov[1], ov[2], ov[3]);
    *(ushort4*)(Sp + 4) = make_ushort4(ov[4], ov[5], ov[6], ov[7]);
}

// ---------------- K4 fast: out = P @ xT^T, fused P-pass, 2-phase dbuf ----------------
__global__ __launch_bounds__(512, 4) void k4_fast(const u16* __restrict__ S,
                                                  const u16* __restrict__ XT,
                                                  float* __restrict__ out)
{
    __shared__ u16 As[2][128 * 64];
    __shared__ u16 Bs[2][128 * 64];
    const int tid = threadIdx.x;
    const int lane = tid & 63, wid = tid >> 6;
    const int wr = (wid >> 1) * 32, wc = (wid & 1) * 64;
    const int l15 = lane & 15, q = lane >> 4;
    const int sw = l15 & 7;
    const int it = (T_ / 128 - 1) - blockIdx.y;   // heavy tiles first
    const int t0 = it * 128;
    const int d0 = blockIdx.x * 128;
    const int b = blockIdx.z;
    const u16* Pb = S + (size_t)b * T_ * T_ + (size_t)t0 * T_;   // raw scores
    const u16* Xb = XT + (size_t)(b * D_ + d0) * T_;

    floatx4 acc[2][4];
#pragma unroll
    for (int i = 0; i < 2; i++)
#pragma unroll
        for (int j = 0; j < 4; j++) acc[i][j] = (floatx4){0.f, 0.f, 0.f, 0.f};

    const int nt = (it + 1) * 2;      // K-steps of 64 up to t0+128 (>= 2)
    {   // prologue: stage K-chunk 0
        uint4 av[2]; float mv[8], rv[8];
        aload(Pb, 0, wid, lane, av);
        mrload(S, b, 0, lane, mv, rv);
        stage8(Xb, T_, 0, Bs[0], wid, lane);
        awrite(As[0], wid, lane, av, mv, rv);
        __syncthreads();
    }
    int cur = 0;
    for (int t = 0; t < nt; t++) {
        uint4 av[2]; float mv[8], rv[8];
        if (t + 1 < nt) {
            aload(Pb, (t + 1) * 64, wid, lane, av);           // issue early
            mrload(S, b, (t + 1) * 64, lane, mv, rv);
            stage8(Xb, T_, (t + 1) * 64, Bs[cur ^ 1], wid, lane);
        }
        gemm_step(As[cur], Bs[cur], wr, wc, l15, q, sw, acc); // loads land here
        if (t + 1 < nt)
            awrite(As[cur ^ 1], wid, lane, av, mv, rv);       // transform late
        __syncthreads();
        cur ^= 1;
    }
#pragma unroll
    for (int i = 0; i < 2; i++)
#pragma unroll
        for (int j = 0; j < 4; j++)
#pragma unroll
            for (int r = 0; r < 4; r++) {
                const int gt = t0 + wr + i * 16 + q * 4 + r;
                const int gd = d0 + wc + j * 16 + l15;
                out[(size_t)(b * T_ + gt) * D_ + gd] = acc[i][j][r];
            }
}

// ---------------- K4 fallback (round-4): scalar-gather B-stage ----------------
__global__ __launch_bounds__(256) void k4_fb(const u16* __restrict__ P,
                                             const float* __restrict__ x,
                                             float* __restrict__ out)
{
    __shared__ u16 As[128 * PIT];
    __shared__ u16 Bs[128 * PIT];
    const int tid = threadIdx.x;
    const int lane = tid & 63, wid = tid >> 6;
    const int wr = (wid >> 1) * 64, wc = (wid & 1) * 64;
    const int l15 = lane & 15, q = lane >> 4;
    const int it = (T_ / 128 - 1) - blockIdx.y;
    const int t0 = it * 128;
    const int d0 = blockIdx.x * 128;
    const int b = blockIdx.z;
    const u16* Pb = P + (size_t)b * T_ * T_;
    const float* xb = x + (size_t)b * T_ * D_;
    const int gn = tid & 127;
    const int kh0 = (tid >> 7) * 2;

    floatx4 acc[4][4];
#pragma unroll
    for (int i = 0; i < 4; i++)
#pragma unroll
        for (int j = 0; j < 4; j++) acc[i][j] = (floatx4){0.f, 0.f, 0.f, 0.f};

    const int kend = t0 + 128;
    for (int k0 = 0; k0 < kend; k0 += 32) {
        __syncthreads();
#pragma unroll
        for (int u = 0; u < 2; u++) {
            const int c = tid * 2 + u;
            const int row = c >> 2, off = c & 3;
            *(uint4*)&As[row * PIT + off * 8] =
                *(const uint4*)(Pb + (size_t)(t0 + row) * T_ + k0 + off * 8);
        }
#pragma unroll
        for (int u = 0; u < 2; u++) {
            const int kh = kh0 + u;
            float f[8];
#pragma unroll
            for (int j = 0; j < 8; j++)
                f[j] = xb[(size_t)(k0 + kh * 8 + j) * D_ + d0 + gn];
            uint4 pk = make_uint4(pkbf(f[0], f[1]), pkbf(f[2], f[3]),
                                  pkbf(f[4], f[5]), pkbf(f[6], f[7]));
            *(uint4*)&Bs[gn * PIT + kh * 8] = pk;
        }
        __syncthreads();
        short8 a[4], b2[4];
#pragma unroll
        for (int i = 0; i < 4; i++) a[i] = *(const short8*)&As[(wr + i * 16 + l15) * PIT + q * 8];
#pragma unroll
        for (int j = 0; j < 4; j++) b2[j] = *(const short8*)&Bs[(wc + j * 16 + l15) * PIT + q * 8];
#pragma unroll
        for (int i = 0; i < 4; i++)
#pragma unroll
            for (int j = 0; j < 4; j++)
                acc[i][j] = __builtin_amdgcn_mfma_f32_16x16x32_bf16(a[i], b2[j], acc[i][j], 0, 0, 0);
    }
#pragma unroll
    for (int i = 0; i < 4; i++)
#pragma unroll
        for (int j = 0; j < 4; j++)
#pragma unroll
            for (int r = 0; r < 4; r++) {
                const int gt = t0 + wr + i * 16 + q * 4 + r;
                const int gd = d0 + wc + j * 16 + l15;
                out[(size_t)(b * T_ + gt) * D_ + gd] = acc[i][j][r];
            }
}

extern "C" void kernel_launch(void* const* d_in, const int* in_sizes, int n_in,
                              void* d_out, int out_size, void* d_ws, size_t ws_size,
                              hipStream_t stream)
{
    const float* x    = (const float*)d_in[0];
    const float* W    = (const float*)d_in[1];
    const float* bias = (const float*)d_in[2];
    float* outf = (float*)d_out;
    u16*   y    = (u16*)d_out;                  // bf16, first 32 MiB of d_out
    u16*   WT   = y + ((size_t)1 << 24);        // 32MiB..34MiB of d_out (dead before k4)
    u16*   S    = (u16*)d_ws;                   // 64 MiB (m/r stashed in dead zone)
    u16*   xbf  = S;                            // bf16 x, ws[0:32MiB] (dead before k2)
    u16*   XT   = S + ((size_t)1 << 25);        // ws+64MiB..+96MiB (fast path only)
    const bool fast = ws_size >= ((size_t)96 << 20);

    dim3 g0(D_ / 64, E_ / 64);            // (16,16)
    k0_wt<<<g0, 256, 0, stream>>>(W, WT);

    dim3 g00(T_ / 64, D_ / 64, B_);       // (32,16,8)
    k00_xt<<<g00, 256, 0, stream>>>(x, XT, xbf, fast ? 1 : 0);

    dim3 g1(E_ / 128, (B_ * T_) / 128);   // (8, 128)
    k1_proj<<<g1, 512, 0, stream>>>(xbf, WT, bias, y);

    dim3 g2(136, B_);
    k2_score<<<g2, 512, 0, stream>>>(y, S);

    dim3 g2b(T_ / 64, B_);                // (32, 8)
    k2b_stats<<<g2b, 256, 0, stream>>>(S);

    dim3 g4(D_ / 128, T_ / 128, B_);      // (8, 16, 8)
    if (fast) {
        k4_fast<<<g4, 512, 0, stream>>>(S, XT, outf);   // k3 fused into A-stage
    } else {
        dim3 g3(B_ * T_);
        k3_pnorm<<<g3, 256, 0, stream>>>(S);
        k4_fb<<<g4, 256, 0, stream>>>(S, x, outf);
    }
}

// Round 5
// 326.197 us; speedup vs baseline: 1.3212x; 1.1635x over previous
//
#include <hip/hip_runtime.h>
#include <hip/hip_bf16.h>

// B=8, T=2048, D=1024, E=1024
//   k0 : WT = bf16(W^T)                 -> d_out[32MiB..34MiB] (dead before k4)
//   k00: xbf = bf16(x) [B][T][D]        -> d_ws[0:32MiB]   (dead before k2 writes S)
//        xT  = bf16(x^T) [B][D][T]      -> d_ws[64MiB..96MiB] (only if ws >= 96MiB)
//   k1 : y = bf16(xbf@WT^T + b)         -> d_out[0:32MiB]  (2-phase dbuf MFMA, BK=64)
//   k2 : S[b,t,s] = bf16(y_t.y_s/32)    -> d_ws, lower-triangle tiles (2-phase dbuf)
//   k2b: col stats m_s, r_s=1/z_s       -> stashed in S's dead zone
//   k3 : P = exp(S-m_s)*r_s in place    (causal-restricted)
//   k4 : out = P @ x  fp32  — fast path: 2-phase dbuf from P and xT.
//
// Round-5: REVERT round-4 k3-fusion (reg-staged A + in-loop exp: k4 68->118us,
//   MfmaUtil 20->12, VALUBusy 15->34 — reg-staging loses gload_lds and the exp
//   stream competes with MFMA issue). Round-2 structure restored (349us).
//   NEW: batch->XCD swizzle (T1) on k2/k4: flat grid, b = blockIdx.x&7 pins
//   batch b to XCD b; y[b] / XT[b] are 4MiB == one XCD L2, so 2-phase staging
//   loads become L2 hits (~200cy) instead of HBM (~900cy) after warmup.
//
// MFMA 16x16x32 bf16 frag layouts (HW-verified):
//   A: lane holds A[m=lane&15][k=q*8+j]; B: B[k=q*8+j][n=lane&15]
//   C/D: lane,reg r -> D[row=q*4+r][col=lane&15]
// Swizzled LDS tile (128 rows x 64 shorts, no pad): 16B chunk slot c of row r
// holds logical chunk c ^ (r&7) (pre-swizzled global source, linear LDS dest).

#define B_ 8
#define T_ 2048
#define D_ 1024
#define E_ 1024
#define PIT 56

typedef unsigned short u16;
typedef __attribute__((ext_vector_type(8))) short short8;
typedef __attribute__((ext_vector_type(4))) float floatx4;

__device__ __forceinline__ float b2f(u16 u) {
    unsigned v = ((unsigned)u) << 16;
    float f; __builtin_memcpy(&f, &v, 4); return f;
}
__device__ __forceinline__ u16 f2b(float f) {
    unsigned v; __builtin_memcpy(&v, &f, 4);
    v = (v + 0x7FFFu + ((v >> 16) & 1u)) >> 16;   // RNE
    return (u16)v;
}
__device__ __forceinline__ unsigned pkbf(float a, float b) {
    __hip_bfloat162 h = __float22bfloat162_rn(make_float2(a, b));
    unsigned u; __builtin_memcpy(&u, &h, 4); return u;
}

// async 16B global -> LDS (lds dest = wave-uniform base + lane*16)
__device__ __forceinline__ void gl2lds16(const u16* gp, u16* lp) {
    __builtin_amdgcn_global_load_lds(
        (const __attribute__((address_space(1))) void*)(gp),
        (__attribute__((address_space(3))) void*)(lp), 16, 0, 0);
}

// 8-wave (512-thread) stage of a 128-row x 64-short bf16 tile into swizzled LDS.
__device__ __forceinline__ void stage8(const u16* src, size_t srow, int kc,
                                       u16* lds, int wid, int lane)
{
    const int rl = lane >> 3, c = lane & 7;
    const int g = ((c ^ rl) << 3);
#pragma unroll
    for (int cc = 0; cc < 2; cc++) {
        const int r = cc * 64 + wid * 8;
        gl2lds16(src + (size_t)(r + rl) * srow + kc + g, &lds[r * 64]);
    }
}

// one BK=64 MFMA step on a staged slot pair (16 mfma)
__device__ __forceinline__ void gemm_step(const u16* As_, const u16* Bs_,
                                          int wr, int wc, int l15, int q, int sw,
                                          floatx4 (&acc)[2][4])
{
#pragma unroll
    for (int h = 0; h < 2; h++) {
        short8 a[2], b2[4];
#pragma unroll
        for (int i = 0; i < 2; i++)
            a[i] = *(const short8*)&As_[(wr + i * 16 + l15) * 64 + (((h * 4 + q) ^ sw) << 3)];
#pragma unroll
        for (int j = 0; j < 4; j++)
            b2[j] = *(const short8*)&Bs_[(wc + j * 16 + l15) * 64 + (((h * 4 + q) ^ sw) << 3)];
#pragma unroll
        for (int i = 0; i < 2; i++)
#pragma unroll
            for (int j = 0; j < 4; j++)
                acc[i][j] = __builtin_amdgcn_mfma_f32_16x16x32_bf16(a[i], b2[j], acc[i][j], 0, 0, 0);
    }
}

// m/r stash inside S's strictly-upper dead zone (batch 0, rows 0..63, cols 1024+).
__device__ __forceinline__ float* mr_ptr(u16* S, int which, int b, int s) {
    const int row = which * 32 + b * 4 + (s >> 9);
    return (float*)(S + (size_t)row * T_ + 1024 + (s & 511) * 2);
}

// ---------------- K0: WT[n][k] = bf16(W[k][n]) ----------------
__global__ __launch_bounds__(256) void k0_wt(const float* __restrict__ W,
                                             u16* __restrict__ WT)
{
    __shared__ float Ws[64 * 68];
    const int tid = threadIdx.x;
    const int k0 = blockIdx.x * 64, n0 = blockIdx.y * 64;
#pragma unroll
    for (int u = 0; u < 4; u++) {
        const int c = tid + 256 * u;
        const int row = c >> 4, c4 = c & 15;
        float4 v = *(const float4*)(W + (size_t)(k0 + row) * E_ + n0 + c4 * 4);
        *(float4*)&Ws[row * 68 + c4 * 4] = v;
    }
    __syncthreads();
#pragma unroll
    for (int u = 0; u < 2; u++) {
        const int c = tid + 256 * u;
        const int n = c >> 3, kc = c & 7;
        unsigned pk[4];
#pragma unroll
        for (int j = 0; j < 4; j++)
            pk[j] = pkbf(Ws[(kc * 8 + 2 * j) * 68 + n], Ws[(kc * 8 + 2 * j + 1) * 68 + n]);
        *(uint4*)(WT + (size_t)(n0 + n) * D_ + k0 + kc * 8) = make_uint4(pk[0], pk[1], pk[2], pk[3]);
    }
}

// ---------------- K00: xbf = bf16(x); optionally xT[b][d][t] = bf16(x[b][t][d]) ----------------
__global__ __launch_bounds__(256) void k00_xt(const float* __restrict__ x,
                                              u16* __restrict__ XT,
                                              u16* __restrict__ xbf,
                                              int do_xt)
{
    __shared__ float Xs[64 * 68];
    const int tid = threadIdx.x;
    const int s0 = blockIdx.x * 64, d0 = blockIdx.y * 64, b = blockIdx.z;
    const float* xb = x + (size_t)b * T_ * D_;
#pragma unroll
    for (int u = 0; u < 4; u++) {
        const int c = tid + 256 * u;
        const int row = c >> 4, c4 = c & 15;
        float4 v = *(const float4*)(xb + (size_t)(s0 + row) * D_ + d0 + c4 * 4);
        *(float4*)&Xs[row * 68 + c4 * 4] = v;
    }
    __syncthreads();
    // row-major bf16 copy (always)
#pragma unroll
    for (int u = 0; u < 2; u++) {
        const int c = tid + 256 * u;
        const int row = c >> 3, off = c & 7;
        unsigned pk[4];
#pragma unroll
        for (int j = 0; j < 4; j++)
            pk[j] = pkbf(Xs[row * 68 + off * 8 + 2 * j], Xs[row * 68 + off * 8 + 2 * j + 1]);
        *(uint4*)(xbf + ((size_t)(b * T_ + s0 + row)) * D_ + d0 + off * 8) =
            make_uint4(pk[0], pk[1], pk[2], pk[3]);
    }
    if (!do_xt) return;
    // transposed bf16 copy (fast path only)
#pragma unroll
    for (int u = 0; u < 2; u++) {
        const int c = tid + 256 * u;
        const int d = c >> 3, sc = c & 7;
        unsigned pk[4];
#pragma unroll
        for (int j = 0; j < 4; j++)
            pk[j] = pkbf(Xs[(sc * 8 + 2 * j) * 68 + d], Xs[(sc * 8 + 2 * j + 1) * 68 + d]);
        *(uint4*)(XT + ((size_t)(b * D_ + d0 + d)) * T_ + s0 + sc * 8) =
            make_uint4(pk[0], pk[1], pk[2], pk[3]);
    }
}

// ---------------- K1: y = bf16(xbf @ WT^T + b), 2-phase dbuf, BK=64 ----------------
__global__ __launch_bounds__(512, 4) void k1_proj(const u16* __restrict__ xbf,
                                                  const u16* __restrict__ WT,
                                                  const float* __restrict__ bias,
                                                  u16* __restrict__ y)
{
    __shared__ u16 As[2][128 * 64];
    __shared__ u16 Bs[2][128 * 64];
    const int tid = threadIdx.x;
    const int lane = tid & 63, wid = tid >> 6;
    const int wr = (wid >> 1) * 32, wc = (wid & 1) * 64;
    const int l15 = lane & 15, q = lane >> 4;
    const int sw = l15 & 7;
    // XCD-chunked swizzle: XCD c owns m-tiles [16c,16c+16) (A panel ~4MB -> L2-hot)
    const int lin = blockIdx.y * 8 + blockIdx.x;      // 1024 blocks, %8==0
    const int v = (lin & 7) * 128 + (lin >> 3);
    const int n0 = (v & 7) * 128, m0 = (v >> 3) * 128;
    const u16* Ab = xbf + (size_t)m0 * D_;
    const u16* Bb = WT + (size_t)n0 * D_;

    floatx4 acc[2][4];
#pragma unroll
    for (int i = 0; i < 2; i++)
#pragma unroll
        for (int j = 0; j < 4; j++) acc[i][j] = (floatx4){0.f, 0.f, 0.f, 0.f};

    stage8(Ab, D_, 0, As[0], wid, lane);
    stage8(Bb, D_, 0, Bs[0], wid, lane);
    __syncthreads();
    int cur = 0;
    for (int t = 0; t < 16; t++) {
        if (t + 1 < 16) {
            stage8(Ab, D_, (t + 1) * 64, As[cur ^ 1], wid, lane);
            stage8(Bb, D_, (t + 1) * 64, Bs[cur ^ 1], wid, lane);
        }
        gemm_step(As[cur], Bs[cur], wr, wc, l15, q, sw, acc);
        __syncthreads();
        cur ^= 1;
    }
    float bv[4];
#pragma unroll
    for (int j = 0; j < 4; j++) bv[j] = bias[n0 + wc + j * 16 + l15];
#pragma unroll
    for (int i = 0; i < 2; i++)
#pragma unroll
        for (int j = 0; j < 4; j++)
#pragma unroll
            for (int r = 0; r < 4; r++) {
                const int gm = m0 + wr + i * 16 + q * 4 + r;
                const int gn = n0 + wc + j * 16 + l15;
                y[(size_t)gm * E_ + gn] = f2b(acc[i][j][r] + bv[j]);
            }
}

// ---------------- K2: S tiles, 2-phase dbuf, BK=64, batch->XCD ----------------
__global__ __launch_bounds__(512, 4) void k2_score(const u16* __restrict__ y,
                                                   u16* __restrict__ S)
{
    __shared__ u16 As[2][128 * 64];
    __shared__ u16 Bs[2][128 * 64];
    const int tid = threadIdx.x;
    const int lane = tid & 63, wid = tid >> 6;
    const int wr = (wid >> 1) * 32, wc = (wid & 1) * 64;
    const int l15 = lane & 15, q = lane >> 4;
    const int sw = l15 & 7;
    // batch->XCD swizzle: flat grid of 1088 = 136 tiles x 8 batches.
    // b = lin&7 pins batch b to XCD b (round-robin dispatch); y[b] = 4MiB = L2.
    const int lin = blockIdx.x;
    const int b = lin & 7;
    int idx = lin >> 3;                  // 0..135 triangular tile id
    int it = 0, base = 0;
    while (base + it + 1 <= idx) { base += it + 1; it++; }
    const int js = idx - base;
    const int t0 = it * 128, s0 = js * 128;
    const u16* yb = y + (size_t)b * T_ * E_;
    const u16* Ab = yb + (size_t)t0 * E_;
    const u16* Bb = yb + (size_t)s0 * E_;

    floatx4 acc[2][4];
#pragma unroll
    for (int i = 0; i < 2; i++)
#pragma unroll
        for (int j = 0; j < 4; j++) acc[i][j] = (floatx4){0.f, 0.f, 0.f, 0.f};

    stage8(Ab, E_, 0, As[0], wid, lane);
    stage8(Bb, E_, 0, Bs[0], wid, lane);
    __syncthreads();
    int cur = 0;
    for (int t = 0; t < 16; t++) {
        if (t + 1 < 16) {
            stage8(Ab, E_, (t + 1) * 64, As[cur ^ 1], wid, lane);
            stage8(Bb, E_, (t + 1) * 64, Bs[cur ^ 1], wid, lane);
        }
        gemm_step(As[cur], Bs[cur], wr, wc, l15, q, sw, acc);
        __syncthreads();
        cur ^= 1;
    }
#pragma unroll
    for (int i = 0; i < 2; i++)
#pragma unroll
        for (int j = 0; j < 4; j++)
#pragma unroll
            for (int r = 0; r < 4; r++) {
                const int t = t0 + wr + i * 16 + q * 4 + r;
                const int s = s0 + wc + j * 16 + l15;
                u16 o = (t < s) ? (u16)0xFF7F : f2b(acc[i][j][r] * 0.03125f);
                S[((size_t)(b * T_ + t)) * T_ + s] = o;
            }
}

// ---------------- K2b: per-column (m, 1/z) over t >= s ----------------
__global__ __launch_bounds__(256) void k2b_stats(u16* __restrict__ S)
{
    __shared__ u16 St[64 * 64];
    __shared__ float sm[4][64], sz[4][64];
    const int tid = threadIdx.x;
    const int lane = tid & 63, w = tid >> 6;
    const int b = blockIdx.y;
    const int s0 = blockIdx.x * 64;
    const u16* Sb = S + (size_t)b * T_ * T_;
    float m = -3e38f, z = 0.f;
    for (int t0 = s0; t0 < T_; t0 += 64) {
        __syncthreads();
#pragma unroll
        for (int u = 0; u < 2; u++) {
            const int c = tid * 2 + u;
            const int row = c >> 3, off = c & 7;
            *(uint4*)&St[row * 64 + off * 8] =
                *(const uint4*)(Sb + (size_t)(t0 + row) * T_ + s0 + off * 8);
        }
        __syncthreads();
#pragma unroll
        for (int i = 0; i < 16; i++) {
            const float v = b2f(St[(w * 16 + i) * 64 + lane]);
            if (v > m) { z = z * __expf(m - v) + 1.f; m = v; }
            else z += __expf(v - m);
        }
    }
    sm[w][lane] = m; sz[w][lane] = z;
    __syncthreads();
    if (tid < 64) {
        float mm = sm[0][tid];
#pragma unroll
        for (int rr = 1; rr < 4; rr++) mm = fmaxf(mm, sm[rr][tid]);
        float zz = 0.f;
#pragma unroll
        for (int rr = 0; rr < 4; rr++) zz += sz[rr][tid] * __expf(sm[rr][tid] - mm);
        *mr_ptr(S, 0, b, s0 + tid) = mm;
        *mr_ptr(S, 1, b, s0 + tid) = 1.0f / zz;
    }
}

// ---------------- K3: P = exp(S - m_s) * r_s  (in place, causal-restricted) ----------------
__global__ __launch_bounds__(256) void k3_pnorm(u16* __restrict__ S)
{
    const int row = blockIdx.x;          // b*T + t
    const int b = row >> 11;
    const int t = row & (T_ - 1);
    const int sEnd = ((t >> 7) + 1) << 7;
    const int s0 = threadIdx.x * 8;
    if (s0 >= sEnd) return;
    u16* Sp = S + (size_t)row * T_ + s0;
    const float* mp = mr_ptr(S, 0, b, s0);
    const float* rp = mr_ptr(S, 1, b, s0);
    float mv[8], rv[8];
    *(float4*)&mv[0] = *(const float4*)mp;
    *(float4*)&mv[4] = *((const float4*)mp + 1);
    *(float4*)&rv[0] = *(const float4*)rp;
    *(float4*)&rv[4] = *((const float4*)rp + 1);
    ushort4 v0 = *(ushort4*)Sp;
    ushort4 v1 = *(ushort4*)(Sp + 4);
    u16 vv[8] = { v0.x, v0.y, v0.z, v0.w, v1.x, v1.y, v1.z, v1.w };
    u16 ov[8];
#pragma unroll
    for (int i = 0; i < 8; i++) {
        const int s = s0 + i;
        float p = 0.f;
        if (s <= t) p = __expf(b2f(vv[i]) - mv[i]) * rv[i];
        ov[i] = f2b(p);
    }
    *(ushort4*)Sp       = make_ushort4(ov[0], ov[1], ov[2], ov[3]);
    *(ushort4*)(Sp + 4) = make_ushort4(ov[4], ov[5], ov[6], ov[7]);
}

// ---------------- K4 fast: out = P @ xT^T, 2-phase dbuf, batch->XCD ----------------
__global__ __launch_bounds__(512, 4) void k4_fast(const u16* __restrict__ P,
                                                  const u16* __restrict__ XT,
                                                  float* __restrict__ out)
{
    __shared__ u16 As[2][128 * 64];
    __shared__ u16 Bs[2][128 * 64];
    const int tid = threadIdx.x;
    const int lane = tid & 63, wid = tid >> 6;
    const int wr = (wid >> 1) * 32, wc = (wid & 1) * 64;
    const int l15 = lane & 15, q = lane >> 4;
    const int sw = l15 & 7;
    // batch->XCD swizzle: flat grid of 1024 = 8 d-blk x 16 it x 8 batches.
    // b = lin&7 pins batch b to XCD b; XT[b] = 4MiB = one XCD's L2.
    const int lin = blockIdx.x;
    const int b = lin & 7;
    const int r8 = lin >> 3;                     // 0..127
    const int d0 = (r8 & 7) * 128;
    const int it = (T_ / 128 - 1) - (r8 >> 3);   // heavy tiles first
    const int t0 = it * 128;
    const u16* Pb = P + (size_t)b * T_ * T_ + (size_t)t0 * T_;
    const u16* Xb = XT + (size_t)(b * D_ + d0) * T_;

    floatx4 acc[2][4];
#pragma unroll
    for (int i = 0; i < 2; i++)
#pragma unroll
        for (int j = 0; j < 4; j++) acc[i][j] = (floatx4){0.f, 0.f, 0.f, 0.f};

    const int nt = (it + 1) * 2;      // K-steps of 64 up to t0+128 (>= 2)
    stage8(Pb, T_, 0, As[0], wid, lane);
    stage8(Xb, T_, 0, Bs[0], wid, lane);
    __syncthreads();
    int cur = 0;
    for (int t = 0; t < nt; t++) {
        if (t + 1 < nt) {
            stage8(Pb, T_, (t + 1) * 64, As[cur ^ 1], wid, lane);
            stage8(Xb, T_, (t + 1) * 64, Bs[cur ^ 1], wid, lane);
        }
        gemm_step(As[cur], Bs[cur], wr, wc, l15, q, sw, acc);
        __syncthreads();
        cur ^= 1;
    }
#pragma unroll
    for (int i = 0; i < 2; i++)
#pragma unroll
        for (int j = 0; j < 4; j++)
#pragma unroll
            for (int r = 0; r < 4; r++) {
                const int gt = t0 + wr + i * 16 + q * 4 + r;
                const int gd = d0 + wc + j * 16 + l15;
                out[(size_t)(b * T_ + gt) * D_ + gd] = acc[i][j][r];
            }
}

// ---------------- K4 fallback (round-4): scalar-gather B-stage ----------------
__global__ __launch_bounds__(256) void k4_fb(const u16* __restrict__ P,
                                             const float* __restrict__ x,
                                             float* __restrict__ out)
{
    __shared__ u16 As[128 * PIT];
    __shared__ u16 Bs[128 * PIT];
    const int tid = threadIdx.x;
    const int lane = tid & 63, wid = tid >> 6;
    const int wr = (wid >> 1) * 64, wc = (wid & 1) * 64;
    const int l15 = lane & 15, q = lane >> 4;
    const int it = (T_ / 128 - 1) - blockIdx.y;
    const int t0 = it * 128;
    const int d0 = blockIdx.x * 128;
    const int b = blockIdx.z;
    const u16* Pb = P + (size_t)b * T_ * T_;
    const float* xb = x + (size_t)b * T_ * D_;
    const int gn = tid & 127;
    const int kh0 = (tid >> 7) * 2;

    floatx4 acc[4][4];
#pragma unroll
    for (int i = 0; i < 4; i++)
#pragma unroll
        for (int j = 0; j < 4; j++) acc[i][j] = (floatx4){0.f, 0.f, 0.f, 0.f};

    const int kend = t0 + 128;
    for (int k0 = 0; k0 < kend; k0 += 32) {
        __syncthreads();
#pragma unroll
        for (int u = 0; u < 2; u++) {
            const int c = tid * 2 + u;
            const int row = c >> 2, off = c & 3;
            *(uint4*)&As[row * PIT + off * 8] =
                *(const uint4*)(Pb + (size_t)(t0 + row) * T_ + k0 + off * 8);
        }
#pragma unroll
        for (int u = 0; u < 2; u++) {
            const int kh = kh0 + u;
            float f[8];
#pragma unroll
            for (int j = 0; j < 8; j++)
                f[j] = xb[(size_t)(k0 + kh * 8 + j) * D_ + d0 + gn];
            uint4 pk = make_uint4(pkbf(f[0], f[1]), pkbf(f[2], f[3]),
                                  pkbf(f[4], f[5]), pkbf(f[6], f[7]));
            *(uint4*)&Bs[gn * PIT + kh * 8] = pk;
        }
        __syncthreads();
        short8 a[4], b2[4];
#pragma unroll
        for (int i = 0; i < 4; i++) a[i] = *(const short8*)&As[(wr + i * 16 + l15) * PIT + q * 8];
#pragma unroll
        for (int j = 0; j < 4; j++) b2[j] = *(const short8*)&Bs[(wc + j * 16 + l15) * PIT + q * 8];
#pragma unroll
        for (int i = 0; i < 4; i++)
#pragma unroll
            for (int j = 0; j < 4; j++)
                acc[i][j] = __builtin_amdgcn_mfma_f32_16x16x32_bf16(a[i], b2[j], acc[i][j], 0, 0, 0);
    }
#pragma unroll
    for (int i = 0; i < 4; i++)
#pragma unroll
        for (int j = 0; j < 4; j++)
#pragma unroll
            for (int r = 0; r < 4; r++) {
                const int gt = t0 + wr + i * 16 + q * 4 + r;
                const int gd = d0 + wc + j * 16 + l15;
                out[(size_t)(b * T_ + gt) * D_ + gd] = acc[i][j][r];
            }
}

extern "C" void kernel_launch(void* const* d_in, const int* in_sizes, int n_in,
                              void* d_out, int out_size, void* d_ws, size_t ws_size,
                              hipStream_t stream)
{
    const float* x    = (const float*)d_in[0];
    const float* W    = (const float*)d_in[1];
    const float* bias = (const float*)d_in[2];
    float* outf = (float*)d_out;
    u16*   y    = (u16*)d_out;                  // bf16, first 32 MiB of d_out
    u16*   WT   = y + ((size_t)1 << 24);        // 32MiB..34MiB of d_out (dead before k4)
    u16*   S    = (u16*)d_ws;                   // 64 MiB (m/r stashed in dead zone)
    u16*   xbf  = S;                            // bf16 x, ws[0:32MiB] (dead before k2)
    u16*   XT   = S + ((size_t)1 << 25);        // ws+64MiB..+96MiB (fast path only)
    const bool fast = ws_size >= ((size_t)96 << 20);

    dim3 g0(D_ / 64, E_ / 64);            // (16,16)
    k0_wt<<<g0, 256, 0, stream>>>(W, WT);

    dim3 g00(T_ / 64, D_ / 64, B_);       // (32,16,8)
    k00_xt<<<g00, 256, 0, stream>>>(x, XT, xbf, fast ? 1 : 0);

    dim3 g1(E_ / 128, (B_ * T_) / 128);   // (8, 128)
    k1_proj<<<g1, 512, 0, stream>>>(xbf, WT, bias, y);

    dim3 g2(136 * B_);                    // flat, batch->XCD
    k2_score<<<g2, 512, 0, stream>>>(y, S);

    dim3 g2b(T_ / 64, B_);                // (32, 8)
    k2b_stats<<<g2b, 256, 0, stream>>>(S);

    dim3 g3(B_ * T_);
    k3_pnorm<<<g3, 256, 0, stream>>>(S);

    dim3 g4((D_ / 128) * (T_ / 128) * B_);   // flat 1024, batch->XCD
    if (fast) k4_fast<<<g4, 512, 0, stream>>>(S, XT, outf);
    else {
        dim3 g4b(D_ / 128, T_ / 128, B_);
        k4_fb<<<g4b, 256, 0, stream>>>(S, x, outf);
    }
}

// Round 6
// 294.330 us; speedup vs baseline: 1.4643x; 1.1083x over previous
//
#include <hip/hip_runtime.h>
#include <hip/hip_bf16.h>

// B=8, T=2048, D=1024, E=1024
//   k0 : WT = bf16(W^T)                 -> d_out[32MiB..34MiB] (dead before k4)
//   k00: xbf = bf16(x) [B][T][D]        -> d_ws[0:32MiB]   (dead before k2 writes S)
//        xT  = bf16(x^T) [B][D][T]      -> d_ws[64MiB..96MiB] (only if ws >= 96MiB)
//   k1 : y = bf16(xbf@WT^T + b)         -> d_out[0:32MiB]  (2-phase dbuf MFMA, BK=64)
//   k2 : S[b,t,s] = bf16(y_t.y_s/32)    -> d_ws, lower-triangle tiles (2-phase dbuf)
//   k2b_part: per-(chunk,col) partial (m,z) -> S dead zone rows 64..575
//   k2c_comb: combine partials -> m_s, r_s=1/z_s stash (rows 0..63)
//   k3 : P = exp(S-m_s)*r_s in place    (causal-restricted)
//   k4 : out = P @ x  fp32  — fast path: 2-phase dbuf from P and xT.
//
// Round-6: k2b was 53us at 5% occupancy / 0.03 of every pipe — 256 blocks and
//   a serial per-element online-softmax chain (cmp->exp->fma x512). Split into
//   k2b_part (2048 blocks, two-pass max-then-sum with independent exps, 4
//   accumulators) + k2c_comb (16K threads, <=8 (m,z) merges). Partials live in
//   S batch-0 dead zone rows 64..575 cols 1024+ (k2 triangular tiles never
//   write there: js<=it => cols>=1024 only for rows>=1024; k4 A-reads reach
//   col <= row|127 <= 639; k2b_part reads have t>=s0 so never rows<=575 with
//   cols>=1024). Round-5 batch->XCD swizzles kept (k2 FETCH 150->34MB).
//
// MFMA 16x16x32 bf16 frag layouts (HW-verified):
//   A: lane holds A[m=lane&15][k=q*8+j]; B: B[k=q*8+j][n=lane&15]
//   C/D: lane,reg r -> D[row=q*4+r][col=lane&15]
// Swizzled LDS tile (128 rows x 64 shorts, no pad): 16B chunk slot c of row r
// holds logical chunk c ^ (r&7) (pre-swizzled global source, linear LDS dest).

#define B_ 8
#define T_ 2048
#define D_ 1024
#define E_ 1024
#define PIT 56
#define NCH 8
#define CHR (T_ / NCH)   // 256 rows per stats chunk

typedef unsigned short u16;
typedef __attribute__((ext_vector_type(8))) short short8;
typedef __attribute__((ext_vector_type(4))) float floatx4;

__device__ __forceinline__ float b2f(u16 u) {
    unsigned v = ((unsigned)u) << 16;
    float f; __builtin_memcpy(&f, &v, 4); return f;
}
__device__ __forceinline__ u16 f2b(float f) {
    unsigned v; __builtin_memcpy(&v, &f, 4);
    v = (v + 0x7FFFu + ((v >> 16) & 1u)) >> 16;   // RNE
    return (u16)v;
}
__device__ __forceinline__ unsigned pkbf(float a, float b) {
    __hip_bfloat162 h = __float22bfloat162_rn(make_float2(a, b));
    unsigned u; __builtin_memcpy(&u, &h, 4); return u;
}

// async 16B global -> LDS (lds dest = wave-uniform base + lane*16)
__device__ __forceinline__ void gl2lds16(const u16* gp, u16* lp) {
    __builtin_amdgcn_global_load_lds(
        (const __attribute__((address_space(1))) void*)(gp),
        (__attribute__((address_space(3))) void*)(lp), 16, 0, 0);
}

// 8-wave (512-thread) stage of a 128-row x 64-short bf16 tile into swizzled LDS.
__device__ __forceinline__ void stage8(const u16* src, size_t srow, int kc,
                                       u16* lds, int wid, int lane)
{
    const int rl = lane >> 3, c = lane & 7;
    const int g = ((c ^ rl) << 3);
#pragma unroll
    for (int cc = 0; cc < 2; cc++) {
        const int r = cc * 64 + wid * 8;
        gl2lds16(src + (size_t)(r + rl) * srow + kc + g, &lds[r * 64]);
    }
}

// one BK=64 MFMA step on a staged slot pair (16 mfma)
__device__ __forceinline__ void gemm_step(const u16* As_, const u16* Bs_,
                                          int wr, int wc, int l15, int q, int sw,
                                          floatx4 (&acc)[2][4])
{
#pragma unroll
    for (int h = 0; h < 2; h++) {
        short8 a[2], b2[4];
#pragma unroll
        for (int i = 0; i < 2; i++)
            a[i] = *(const short8*)&As_[(wr + i * 16 + l15) * 64 + (((h * 4 + q) ^ sw) << 3)];
#pragma unroll
        for (int j = 0; j < 4; j++)
            b2[j] = *(const short8*)&Bs_[(wc + j * 16 + l15) * 64 + (((h * 4 + q) ^ sw) << 3)];
#pragma unroll
        for (int i = 0; i < 2; i++)
#pragma unroll
            for (int j = 0; j < 4; j++)
                acc[i][j] = __builtin_amdgcn_mfma_f32_16x16x32_bf16(a[i], b2[j], acc[i][j], 0, 0, 0);
    }
}

// m/r stash inside S's strictly-upper dead zone (batch 0, rows 0..63, cols 1024+).
__device__ __forceinline__ float* mr_ptr(u16* S, int which, int b, int s) {
    const int row = which * 32 + b * 4 + (s >> 9);
    return (float*)(S + (size_t)row * T_ + 1024 + (s & 511) * 2);
}
// per-chunk partial (m,z): rows 64..319 (m) / 320..575 (z), cols 1024+ of batch 0.
__device__ __forceinline__ float* part_ptr(u16* S, int which, int c, int b, int s) {
    const int row = 64 + which * 256 + (c * 8 + b) * 4 + (s >> 9);
    return (float*)(S + (size_t)row * T_ + 1024 + (s & 511) * 2);
}

// ---------------- K0: WT[n][k] = bf16(W[k][n]) ----------------
__global__ __launch_bounds__(256) void k0_wt(const float* __restrict__ W,
                                             u16* __restrict__ WT)
{
    __shared__ float Ws[64 * 68];
    const int tid = threadIdx.x;
    const int k0 = blockIdx.x * 64, n0 = blockIdx.y * 64;
#pragma unroll
    for (int u = 0; u < 4; u++) {
        const int c = tid + 256 * u;
        const int row = c >> 4, c4 = c & 15;
        float4 v = *(const float4*)(W + (size_t)(k0 + row) * E_ + n0 + c4 * 4);
        *(float4*)&Ws[row * 68 + c4 * 4] = v;
    }
    __syncthreads();
#pragma unroll
    for (int u = 0; u < 2; u++) {
        const int c = tid + 256 * u;
        const int n = c >> 3, kc = c & 7;
        unsigned pk[4];
#pragma unroll
        for (int j = 0; j < 4; j++)
            pk[j] = pkbf(Ws[(kc * 8 + 2 * j) * 68 + n], Ws[(kc * 8 + 2 * j + 1) * 68 + n]);
        *(uint4*)(WT + (size_t)(n0 + n) * D_ + k0 + kc * 8) = make_uint4(pk[0], pk[1], pk[2], pk[3]);
    }
}

// ---------------- K00: xbf = bf16(x); optionally xT[b][d][t] = bf16(x[b][t][d]) ----------------
__global__ __launch_bounds__(256) void k00_xt(const float* __restrict__ x,
                                              u16* __restrict__ XT,
                                              u16* __restrict__ xbf,
                                              int do_xt)
{
    __shared__ float Xs[64 * 68];
    const int tid = threadIdx.x;
    const int s0 = blockIdx.x * 64, d0 = blockIdx.y * 64, b = blockIdx.z;
    const float* xb = x + (size_t)b * T_ * D_;
#pragma unroll
    for (int u = 0; u < 4; u++) {
        const int c = tid + 256 * u;
        const int row = c >> 4, c4 = c & 15;
        float4 v = *(const float4*)(xb + (size_t)(s0 + row) * D_ + d0 + c4 * 4);
        *(float4*)&Xs[row * 68 + c4 * 4] = v;
    }
    __syncthreads();
    // row-major bf16 copy (always)
#pragma unroll
    for (int u = 0; u < 2; u++) {
        const int c = tid + 256 * u;
        const int row = c >> 3, off = c & 7;
        unsigned pk[4];
#pragma unroll
        for (int j = 0; j < 4; j++)
            pk[j] = pkbf(Xs[row * 68 + off * 8 + 2 * j], Xs[row * 68 + off * 8 + 2 * j + 1]);
        *(uint4*)(xbf + ((size_t)(b * T_ + s0 + row)) * D_ + d0 + off * 8) =
            make_uint4(pk[0], pk[1], pk[2], pk[3]);
    }
    if (!do_xt) return;
    // transposed bf16 copy (fast path only)
#pragma unroll
    for (int u = 0; u < 2; u++) {
        const int c = tid + 256 * u;
        const int d = c >> 3, sc = c & 7;
        unsigned pk[4];
#pragma unroll
        for (int j = 0; j < 4; j++)
            pk[j] = pkbf(Xs[(sc * 8 + 2 * j) * 68 + d], Xs[(sc * 8 + 2 * j + 1) * 68 + d]);
        *(uint4*)(XT + ((size_t)(b * D_ + d0 + d)) * T_ + s0 + sc * 8) =
            make_uint4(pk[0], pk[1], pk[2], pk[3]);
    }
}

// ---------------- K1: y = bf16(xbf @ WT^T + b), 2-phase dbuf, BK=64 ----------------
__global__ __launch_bounds__(512, 4) void k1_proj(const u16* __restrict__ xbf,
                                                  const u16* __restrict__ WT,
                                                  const float* __restrict__ bias,
                                                  u16* __restrict__ y)
{
    __shared__ u16 As[2][128 * 64];
    __shared__ u16 Bs[2][128 * 64];
    const int tid = threadIdx.x;
    const int lane = tid & 63, wid = tid >> 6;
    const int wr = (wid >> 1) * 32, wc = (wid & 1) * 64;
    const int l15 = lane & 15, q = lane >> 4;
    const int sw = l15 & 7;
    // XCD-chunked swizzle: XCD c owns m-tiles [16c,16c+16) (A panel ~4MB -> L2-hot)
    const int lin = blockIdx.y * 8 + blockIdx.x;      // 1024 blocks, %8==0
    const int v = (lin & 7) * 128 + (lin >> 3);
    const int n0 = (v & 7) * 128, m0 = (v >> 3) * 128;
    const u16* Ab = xbf + (size_t)m0 * D_;
    const u16* Bb = WT + (size_t)n0 * D_;

    floatx4 acc[2][4];
#pragma unroll
    for (int i = 0; i < 2; i++)
#pragma unroll
        for (int j = 0; j < 4; j++) acc[i][j] = (floatx4){0.f, 0.f, 0.f, 0.f};

    stage8(Ab, D_, 0, As[0], wid, lane);
    stage8(Bb, D_, 0, Bs[0], wid, lane);
    __syncthreads();
    int cur = 0;
    for (int t = 0; t < 16; t++) {
        if (t + 1 < 16) {
            stage8(Ab, D_, (t + 1) * 64, As[cur ^ 1], wid, lane);
            stage8(Bb, D_, (t + 1) * 64, Bs[cur ^ 1], wid, lane);
        }
        gemm_step(As[cur], Bs[cur], wr, wc, l15, q, sw, acc);
        __syncthreads();
        cur ^= 1;
    }
    float bv[4];
#pragma unroll
    for (int j = 0; j < 4; j++) bv[j] = bias[n0 + wc + j * 16 + l15];
#pragma unroll
    for (int i = 0; i < 2; i++)
#pragma unroll
        for (int j = 0; j < 4; j++)
#pragma unroll
            for (int r = 0; r < 4; r++) {
                const int gm = m0 + wr + i * 16 + q * 4 + r;
                const int gn = n0 + wc + j * 16 + l15;
                y[(size_t)gm * E_ + gn] = f2b(acc[i][j][r] + bv[j]);
            }
}

// ---------------- K2: S tiles, 2-phase dbuf, BK=64, batch->XCD ----------------
__global__ __launch_bounds__(512, 4) void k2_score(const u16* __restrict__ y,
                                                   u16* __restrict__ S)
{
    __shared__ u16 As[2][128 * 64];
    __shared__ u16 Bs[2][128 * 64];
    const int tid = threadIdx.x;
    const int lane = tid & 63, wid = tid >> 6;
    const int wr = (wid >> 1) * 32, wc = (wid & 1) * 64;
    const int l15 = lane & 15, q = lane >> 4;
    const int sw = l15 & 7;
    // batch->XCD swizzle: flat grid of 1088 = 136 tiles x 8 batches.
    // b = lin&7 pins batch b to XCD b (round-robin dispatch); y[b] = 4MiB = L2.
    const int lin = blockIdx.x;
    const int b = lin & 7;
    int idx = lin >> 3;                  // 0..135 triangular tile id
    int it = 0, base = 0;
    while (base + it + 1 <= idx) { base += it + 1; it++; }
    const int js = idx - base;
    const int t0 = it * 128, s0 = js * 128;
    const u16* yb = y + (size_t)b * T_ * E_;
    const u16* Ab = yb + (size_t)t0 * E_;
    const u16* Bb = yb + (size_t)s0 * E_;

    floatx4 acc[2][4];
#pragma unroll
    for (int i = 0; i < 2; i++)
#pragma unroll
        for (int j = 0; j < 4; j++) acc[i][j] = (floatx4){0.f, 0.f, 0.f, 0.f};

    stage8(Ab, E_, 0, As[0], wid, lane);
    stage8(Bb, E_, 0, Bs[0], wid, lane);
    __syncthreads();
    int cur = 0;
    for (int t = 0; t < 16; t++) {
        if (t + 1 < 16) {
            stage8(Ab, E_, (t + 1) * 64, As[cur ^ 1], wid, lane);
            stage8(Bb, E_, (t + 1) * 64, Bs[cur ^ 1], wid, lane);
        }
        gemm_step(As[cur], Bs[cur], wr, wc, l15, q, sw, acc);
        __syncthreads();
        cur ^= 1;
    }
#pragma unroll
    for (int i = 0; i < 2; i++)
#pragma unroll
        for (int j = 0; j < 4; j++)
#pragma unroll
            for (int r = 0; r < 4; r++) {
                const int t = t0 + wr + i * 16 + q * 4 + r;
                const int s = s0 + wc + j * 16 + l15;
                u16 o = (t < s) ? (u16)0xFF7F : f2b(acc[i][j][r] * 0.03125f);
                S[((size_t)(b * T_ + t)) * T_ + s] = o;
            }
}

// ---------------- K2b_part: per-(chunk,col) partial (m, z) over t in chunk ----------------
__global__ __launch_bounds__(256) void k2b_part(u16* __restrict__ S)
{
    __shared__ u16 St[CHR * 64];          // 32 KiB
    __shared__ float sm[4][64], sz[4][64];
    const int tid = threadIdx.x;
    const int lane = tid & 63, w = tid >> 6;
    const int s0 = blockIdx.x * 64;
    const int c  = blockIdx.y;
    const int b  = blockIdx.z;
    const int tb = max(c * CHR, s0);      // causal: only t >= s0 (64-aligned)
    const int te = (c + 1) * CHR;
    if (tb >= te) return;                 // chunk entirely above this column strip
    const int R = te - tb;                // multiple of 64
    const u16* Sb = S + (size_t)b * T_ * T_;
    // stage R x 64 tile (rows are 128B contiguous; 32 rows per 256-thread round)
    for (int r0 = 0; r0 < R; r0 += 32) {
        const int row = r0 + (tid >> 3), off = tid & 7;
        *(uint4*)&St[row * 64 + off * 8] =
            *(const uint4*)(Sb + (size_t)(tb + row) * T_ + s0 + off * 8);
    }
    __syncthreads();
    // thread (w,lane): rows [w*64, w*64+64) of column lane; two-pass, 4 accums.
    const int rb = w * 64;
    float m4[4] = {-3e38f, -3e38f, -3e38f, -3e38f};
    float z4[4] = {0.f, 0.f, 0.f, 0.f};
    float mt = -3e38f;
    if (rb < R) {
#pragma unroll 4
        for (int i = 0; i < 64; i += 4)
#pragma unroll
            for (int j = 0; j < 4; j++)
                m4[j] = fmaxf(m4[j], b2f(St[(rb + i + j) * 64 + lane]));
        mt = fmaxf(fmaxf(m4[0], m4[1]), fmaxf(m4[2], m4[3]));
#pragma unroll 4
        for (int i = 0; i < 64; i += 4)
#pragma unroll
            for (int j = 0; j < 4; j++)
                z4[j] += __expf(b2f(St[(rb + i + j) * 64 + lane]) - mt);
    }
    sm[w][lane] = mt;
    sz[w][lane] = (z4[0] + z4[1]) + (z4[2] + z4[3]);
    __syncthreads();
    if (tid < 64) {
        float mm = sm[0][tid];
#pragma unroll
        for (int rr = 1; rr < 4; rr++) mm = fmaxf(mm, sm[rr][tid]);
        float zz = 0.f;
#pragma unroll
        for (int rr = 0; rr < 4; rr++) zz += sz[rr][tid] * __expf(sm[rr][tid] - mm);
        *part_ptr(S, 0, c, b, s0 + tid) = mm;
        *part_ptr(S, 1, c, b, s0 + tid) = zz;
    }
}

// ---------------- K2c_comb: combine <=8 chunk partials -> (m, 1/z) stash ----------------
__global__ __launch_bounds__(256) void k2c_comb(u16* __restrict__ S)
{
    const int s = blockIdx.x * 256 + threadIdx.x;
    const int b = blockIdx.y;
    float M = -3e38f, Z = 0.f;
    for (int c = s >> 8; c < NCH; c++) {      // chunks below s0 were never written
        const float mc = *part_ptr(S, 0, c, b, s);
        const float zc = *part_ptr(S, 1, c, b, s);
        if (mc > M) { Z = Z * __expf(M - mc) + zc; M = mc; }
        else        { Z += zc * __expf(mc - M); }
    }
    *mr_ptr(S, 0, b, s) = M;
    *mr_ptr(S, 1, b, s) = 1.0f / Z;
}

// ---------------- K3: P = exp(S - m_s) * r_s  (in place, causal-restricted) ----------------
__global__ __launch_bounds__(256) void k3_pnorm(u16* __restrict__ S)
{
    const int row = blockIdx.x;          // b*T + t
    const int b = row >> 11;
    const int t = row & (T_ - 1);
    const int sEnd = ((t >> 7) + 1) << 7;
    const int s0 = threadIdx.x * 8;
    if (s0 >= sEnd) return;
    u16* Sp = S + (size_t)row * T_ + s0;
    const float* mp = mr_ptr(S, 0, b, s0);
    const float* rp = mr_ptr(S, 1, b, s0);
    float mv[8], rv[8];
    *(float4*)&mv[0] = *(const float4*)mp;
    *(float4*)&mv[4] = *((const float4*)mp + 1);
    *(float4*)&rv[0] = *(const float4*)rp;
    *(float4*)&rv[4] = *((const float4*)rp + 1);
    ushort4 v0 = *(ushort4*)Sp;
    ushort4 v1 = *(ushort4*)(Sp + 4);
    u16 vv[8] = { v0.x, v0.y, v0.z, v0.w, v1.x, v1.y, v1.z, v1.w };
    u16 ov[8];
#pragma unroll
    for (int i = 0; i < 8; i++) {
        const int s = s0 + i;
        float p = 0.f;
        if (s <= t) p = __expf(b2f(vv[i]) - mv[i]) * rv[i];
        ov[i] = f2b(p);
    }
    *(ushort4*)Sp       = make_ushort4(ov[0], ov[1], ov[2], ov[3]);
    *(ushort4*)(Sp + 4) = make_ushort4(ov[4], ov[5], ov[6], ov[7]);
}

// ---------------- K4 fast: out = P @ xT^T, 2-phase dbuf, batch->XCD ----------------
__global__ __launch_bounds__(512, 4) void k4_fast(const u16* __restrict__ P,
                                                  const u16* __restrict__ XT,
                                                  float* __restrict__ out)
{
    __shared__ u16 As[2][128 * 64];
    __shared__ u16 Bs[2][128 * 64];
    const int tid = threadIdx.x;
    const int lane = tid & 63, wid = tid >> 6;
    const int wr = (wid >> 1) * 32, wc = (wid & 1) * 64;
    const int l15 = lane & 15, q = lane >> 4;
    const int sw = l15 & 7;
    // batch->XCD swizzle: flat grid of 1024 = 8 d-blk x 16 it x 8 batches.
    // b = lin&7 pins batch b to XCD b; XT[b] = 4MiB = one XCD's L2.
    const int lin = blockIdx.x;
    const int b = lin & 7;
    const int r8 = lin >> 3;                     // 0..127
    const int d0 = (r8 & 7) * 128;
    const int it = (T_ / 128 - 1) - (r8 >> 3);   // heavy tiles first
    const int t0 = it * 128;
    const u16* Pb = P + (size_t)b * T_ * T_ + (size_t)t0 * T_;
    const u16* Xb = XT + (size_t)(b * D_ + d0) * T_;

    floatx4 acc[2][4];
#pragma unroll
    for (int i = 0; i < 2; i++)
#pragma unroll
        for (int j = 0; j < 4; j++) acc[i][j] = (floatx4){0.f, 0.f, 0.f, 0.f};

    const int nt = (it + 1) * 2;      // K-steps of 64 up to t0+128 (>= 2)
    stage8(Pb, T_, 0, As[0], wid, lane);
    stage8(Xb, T_, 0, Bs[0], wid, lane);
    __syncthreads();
    int cur = 0;
    for (int t = 0; t < nt; t++) {
        if (t + 1 < nt) {
            stage8(Pb, T_, (t + 1) * 64, As[cur ^ 1], wid, lane);
            stage8(Xb, T_, (t + 1) * 64, Bs[cur ^ 1], wid, lane);
        }
        gemm_step(As[cur], Bs[cur], wr, wc, l15, q, sw, acc);
        __syncthreads();
        cur ^= 1;
    }
#pragma unroll
    for (int i = 0; i < 2; i++)
#pragma unroll
        for (int j = 0; j < 4; j++)
#pragma unroll
            for (int r = 0; r < 4; r++) {
                const int gt = t0 + wr + i * 16 + q * 4 + r;
                const int gd = d0 + wc + j * 16 + l15;
                out[(size_t)(b * T_ + gt) * D_ + gd] = acc[i][j][r];
            }
}

// ---------------- K4 fallback (round-4): scalar-gather B-stage ----------------
__global__ __launch_bounds__(256) void k4_fb(const u16* __restrict__ P,
                                             const float* __restrict__ x,
                                             float* __restrict__ out)
{
    __shared__ u16 As[128 * PIT];
    __shared__ u16 Bs[128 * PIT];
    const int tid = threadIdx.x;
    const int lane = tid & 63, wid = tid >> 6;
    const int wr = (wid >> 1) * 64, wc = (wid & 1) * 64;
    const int l15 = lane & 15, q = lane >> 4;
    const int it = (T_ / 128 - 1) - blockIdx.y;
    const int t0 = it * 128;
    const int d0 = blockIdx.x * 128;
    const int b = blockIdx.z;
    const u16* Pb = P + (size_t)b * T_ * T_;
    const float* xb = x + (size_t)b * T_ * D_;
    const int gn = tid & 127;
    const int kh0 = (tid >> 7) * 2;

    floatx4 acc[4][4];
#pragma unroll
    for (int i = 0; i < 4; i++)
#pragma unroll
        for (int j = 0; j < 4; j++) acc[i][j] = (floatx4){0.f, 0.f, 0.f, 0.f};

    const int kend = t0 + 128;
    for (int k0 = 0; k0 < kend; k0 += 32) {
        __syncthreads();
#pragma unroll
        for (int u = 0; u < 2; u++) {
            const int c = tid * 2 + u;
            const int row = c >> 2, off = c & 3;
            *(uint4*)&As[row * PIT + off * 8] =
                *(const uint4*)(Pb + (size_t)(t0 + row) * T_ + k0 + off * 8);
        }
#pragma unroll
        for (int u = 0; u < 2; u++) {
            const int kh = kh0 + u;
            float f[8];
#pragma unroll
            for (int j = 0; j < 8; j++)
                f[j] = xb[(size_t)(k0 + kh * 8 + j) * D_ + d0 + gn];
            uint4 pk = make_uint4(pkbf(f[0], f[1]), pkbf(f[2], f[3]),
                                  pkbf(f[4], f[5]), pkbf(f[6], f[7]));
            *(uint4*)&Bs[gn * PIT + kh * 8] = pk;
        }
        __syncthreads();
        short8 a[4], b2[4];
#pragma unroll
        for (int i = 0; i < 4; i++) a[i] = *(const short8*)&As[(wr + i * 16 + l15) * PIT + q * 8];
#pragma unroll
        for (int j = 0; j < 4; j++) b2[j] = *(const short8*)&Bs[(wc + j * 16 + l15) * PIT + q * 8];
#pragma unroll
        for (int i = 0; i < 4; i++)
#pragma unroll
            for (int j = 0; j < 4; j++)
                acc[i][j] = __builtin_amdgcn_mfma_f32_16x16x32_bf16(a[i], b2[j], acc[i][j], 0, 0, 0);
    }
#pragma unroll
    for (int i = 0; i < 4; i++)
#pragma unroll
        for (int j = 0; j < 4; j++)
#pragma unroll
            for (int r = 0; r < 4; r++) {
                const int gt = t0 + wr + i * 16 + q * 4 + r;
                const int gd = d0 + wc + j * 16 + l15;
                out[(size_t)(b * T_ + gt) * D_ + gd] = acc[i][j][r];
            }
}

extern "C" void kernel_launch(void* const* d_in, const int* in_sizes, int n_in,
                              void* d_out, int out_size, void* d_ws, size_t ws_size,
                              hipStream_t stream)
{
    const float* x    = (const float*)d_in[0];
    const float* W    = (const float*)d_in[1];
    const float* bias = (const float*)d_in[2];
    float* outf = (float*)d_out;
    u16*   y    = (u16*)d_out;                  // bf16, first 32 MiB of d_out
    u16*   WT   = y + ((size_t)1 << 24);        // 32MiB..34MiB of d_out (dead before k4)
    u16*   S    = (u16*)d_ws;                   // 64 MiB (m/r + partials in dead zone)
    u16*   xbf  = S;                            // bf16 x, ws[0:32MiB] (dead before k2)
    u16*   XT   = S + ((size_t)1 << 25);        // ws+64MiB..+96MiB (fast path only)
    const bool fast = ws_size >= ((size_t)96 << 20);

    dim3 g0(D_ / 64, E_ / 64);            // (16,16)
    k0_wt<<<g0, 256, 0, stream>>>(W, WT);

    dim3 g00(T_ / 64, D_ / 64, B_);       // (32,16,8)
    k00_xt<<<g00, 256, 0, stream>>>(x, XT, xbf, fast ? 1 : 0);

    dim3 g1(E_ / 128, (B_ * T_) / 128);   // (8, 128)
    k1_proj<<<g1, 512, 0, stream>>>(xbf, WT, bias, y);

    dim3 g2(136 * B_);                    // flat, batch->XCD
    k2_score<<<g2, 512, 0, stream>>>(y, S);

    dim3 gp(T_ / 64, NCH, B_);            // (32, 8, 8) = 2048 blocks
    k2b_part<<<gp, 256, 0, stream>>>(S);

    dim3 gc(T_ / 256, B_);                // (8, 8)
    k2c_comb<<<gc, 256, 0, stream>>>(S);

    dim3 g3(B_ * T_);
    k3_pnorm<<<g3, 256, 0, stream>>>(S);

    dim3 g4((D_ / 128) * (T_ / 128) * B_);   // flat 1024, batch->XCD
    if (fast) k4_fast<<<g4, 512, 0, stream>>>(S, XT, outf);
    else {
        dim3 g4b(D_ / 128, T_ / 128, B_);
        k4_fb<<<g4b, 256, 0, stream>>>(S, x, outf);
    }
}